// Round 1
// baseline (945.921 us; speedup 1.0000x reference)
//
#include <hip/hip_runtime.h>
#include <cstdint>
#include <cstddef>

// Problem constants
#define B_   2
#define L_   2048
#define IN_  128
#define H_   512
#define OUT_ 64
#define NL_  2
#define ED_  1024
#define N_   16
#define DR_  32
#define K_   4

static constexpr int M_TOK = B_ * L_;   // 4096 tokens
static constexpr int SEG   = 32;        // scan segments
static constexpr int TS    = L_ / SEG;  // 64 steps per segment

// ---------------------------------------------------------------------------
// Generic tiled f32 GEMM: C[M,N] = epilogue(A[M,K] @ W[K,N])
// 64x64 tile, BK=16, 256 threads, 4x4 micro-tile per thread.
// ACT: 0=none, 1=tanh, 2=softplus. RES: C += result. FINALSUB: v -= tanh(v).
// ---------------------------------------------------------------------------
template<int ACT, bool BIAS1, bool BIAS2, bool RES, bool FINALSUB>
__global__ __launch_bounds__(256)
void gemm_f32(const float* __restrict__ A, int lda,
              const float* __restrict__ W, int ldw,
              const float* __restrict__ b1, const float* __restrict__ b2,
              float* C, int ldc, int M, int N, int K)
{
    // pad 68 (=17*16B rows): float4-aligned, 2-way-max bank aliasing (free)
    __shared__ __align__(16) float As[16][68];
    __shared__ __align__(16) float Ws[16][68];

    const int tid = threadIdx.x;
    const int bm = blockIdx.x * 64;
    const int bn = blockIdx.y * 64;
    const int tx = tid & 15, ty = tid >> 4;

    // staging index maps (one float4 per thread per tile)
    const int ar  = tid >> 2;            // A-tile row (0..63)
    const int acq = (tid & 3) * 4;       // A-tile col quad (0..12)
    const int wr  = tid >> 4;            // W-tile row (0..15)
    const int wc  = (tid & 15) * 4;      // W-tile col quad

    float acc[4][4] = {};

    for (int k0 = 0; k0 < K; k0 += 16) {
        float4 av4 = *reinterpret_cast<const float4*>(
            &A[(size_t)(bm + ar) * lda + k0 + acq]);
        float4 wv4 = *reinterpret_cast<const float4*>(
            &W[(size_t)(k0 + wr) * ldw + bn + wc]);
        As[acq + 0][ar] = av4.x;
        As[acq + 1][ar] = av4.y;
        As[acq + 2][ar] = av4.z;
        As[acq + 3][ar] = av4.w;
        *reinterpret_cast<float4*>(&Ws[wr][wc]) = wv4;
        __syncthreads();

        #pragma unroll
        for (int kk = 0; kk < 16; ++kk) {
            float4 a = *reinterpret_cast<const float4*>(&As[kk][ty * 4]);
            float4 b = *reinterpret_cast<const float4*>(&Ws[kk][tx * 4]);
            float aa[4] = {a.x, a.y, a.z, a.w};
            float bb[4] = {b.x, b.y, b.z, b.w};
            #pragma unroll
            for (int i = 0; i < 4; ++i)
                #pragma unroll
                for (int j = 0; j < 4; ++j)
                    acc[i][j] = fmaf(aa[i], bb[j], acc[i][j]);
        }
        __syncthreads();
    }

    #pragma unroll
    for (int i = 0; i < 4; ++i) {
        const int row = bm + ty * 4 + i;
        #pragma unroll
        for (int j = 0; j < 4; ++j) {
            const int col = bn + tx * 4 + j;
            float v = acc[i][j];
            if (BIAS1) v += b1[col];
            if (BIAS2) v += b2[col];
            if (ACT == 1) v = tanhf(v);
            if (ACT == 2) v = fmaxf(v, 0.0f) + log1pf(expf(-fabsf(v)));  // softplus
            float* cp = C + (size_t)row * ldc + col;
            if (RES) v += *cp;
            if (FINALSUB) v = v - tanhf(v);
            *cp = v;
        }
    }
}

// ---------------------------------------------------------------------------
// RMSNorm over H=512, one block per token (256 thr x 2 elems)
// ---------------------------------------------------------------------------
__global__ __launch_bounds__(256)
void rmsnorm_k(const float* __restrict__ x, const float* __restrict__ w,
               float* __restrict__ o)
{
    const int row = blockIdx.x;
    const int tid = threadIdx.x;
    const float* xr = x + (size_t)row * H_;
    float v0 = xr[tid], v1 = xr[tid + 256];
    float s = v0 * v0 + v1 * v1;
    #pragma unroll
    for (int off = 32; off > 0; off >>= 1) s += __shfl_down(s, off, 64);
    __shared__ float ps[4];
    __shared__ float scale_s;
    const int wave = tid >> 6, lane = tid & 63;
    if (lane == 0) ps[wave] = s;
    __syncthreads();
    if (tid == 0) {
        float tot = ps[0] + ps[1] + ps[2] + ps[3];
        scale_s = rsqrtf(tot * (1.0f / H_) + 1e-5f);
    }
    __syncthreads();
    const float sc = scale_s;
    o[(size_t)row * H_ + tid]       = v0 * sc * w[tid];
    o[(size_t)row * H_ + tid + 256] = v1 * sc * w[tid + 256];
}

// ---------------------------------------------------------------------------
// Depthwise causal conv (K=4) + SiLU. Input = first half of xz rows (2*ED wide)
// y[t] = w0*x[t-3] + w1*x[t-2] + w2*x[t-1] + w3*x[t] + b  (lax correlation)
// ---------------------------------------------------------------------------
__global__ __launch_bounds__(256)
void conv_silu_k(const float* __restrict__ xz, const float* __restrict__ cw,
                 const float* __restrict__ cb, float* __restrict__ xc)
{
    const int idx = blockIdx.x * 256 + threadIdx.x;   // over B*L*ED
    const int d = idx & (ED_ - 1);
    const int t = (idx >> 10) & (L_ - 1);
    const int b = idx >> 21;
    const size_t base = (size_t)(b * L_ + t) * (2 * ED_) + d;
    float4 w = *reinterpret_cast<const float4*>(&cw[d * 4]);
    float acc = cb[d];
    acc += w.w * xz[base];
    if (t >= 1) acc += w.z * xz[base - 1 * 2 * ED_];
    if (t >= 2) acc += w.y * xz[base - 2 * 2 * ED_];
    if (t >= 3) acc += w.x * xz[base - 3 * 2 * ED_];
    const float s = acc / (1.0f + expf(-acc));  // silu
    xc[(size_t)(b * L_ + t) * ED_ + d] = s;
}

// ---------------------------------------------------------------------------
// SSM chunked scan.
// Phase 1 (!P3): per segment, zero-init recurrence -> hend, pprod.
// Phase 3 ( P3): re-run with correct hinit, emit y = (sum h*C + D*x)*silu(z).
// hend/pprod/hinit layout: [b][seg][n][d]  (d fastest -> coalesced)
// ybuf may alias delta (same element read-before-write per thread) -> no restrict.
// ---------------------------------------------------------------------------
template<bool P3>
__global__ __launch_bounds__(256)
void ssm_scan_k(const float* delta,                 // (M_TOK, ED)
                const float* __restrict__ xc,       // (M_TOK, ED)
                const float* __restrict__ dbl,      // (M_TOK, 64)
                const float* __restrict__ xz,       // (M_TOK, 2*ED) for z (P3)
                const float* __restrict__ A_log,    // (ED, N) layer base
                const float* __restrict__ Dv,       // (ED)
                float* __restrict__ hend, float* __restrict__ pprod,
                const float* __restrict__ hinit,
                float* ybuf)                        // (M_TOK, ED)
{
    __shared__ float bc[TS][32];   // [t][0:16]=B, [t][16:32]=C
    const int bx   = blockIdx.x;
    const int seg  = bx & (SEG - 1);
    const int dblk = (bx >> 5) & 3;
    const int b    = bx >> 7;
    const int tid  = threadIdx.x;
    const int d    = dblk * 256 + tid;
    const int t0   = seg * TS;

    #pragma unroll
    for (int e = 0; e < (TS * 32) / 256; ++e) {
        int lin = tid + e * 256;
        int tr = lin >> 5, j = lin & 31;
        bc[tr][j] = dbl[(size_t)(b * L_ + t0 + tr) * 64 + 32 + j];
    }
    __syncthreads();

    float Av[N_];
    #pragma unroll
    for (int n = 0; n < N_; ++n) Av[n] = -expf(A_log[d * N_ + n]);

    float h[N_], P[N_];
    if (P3) {
        #pragma unroll
        for (int n = 0; n < N_; ++n)
            h[n] = hinit[((size_t)(b * SEG + seg) * N_ + n) * ED_ + d];
    } else {
        #pragma unroll
        for (int n = 0; n < N_; ++n) { h[n] = 0.0f; P[n] = 1.0f; }
    }
    float Dd = 0.0f;
    if (P3) Dd = Dv[d];

    for (int tt = 0; tt < TS; ++tt) {
        const size_t row = (size_t)(b * L_ + t0 + tt);
        const float dv = delta[row * ED_ + d];
        const float xv = xc[row * ED_ + d];
        const float dx = dv * xv;
        float ysum = 0.0f;
        #pragma unroll
        for (int n = 0; n < N_; ++n) {
            const float dA = expf(dv * Av[n]);
            h[n] = fmaf(dA, h[n], dx * bc[tt][n]);
            if (!P3) P[n] *= dA;
            else     ysum = fmaf(h[n], bc[tt][16 + n], ysum);
        }
        if (P3) {
            const float zv = xz[row * (2 * ED_) + ED_ + d];
            const float sz = zv / (1.0f + expf(-zv));
            ybuf[row * ED_ + d] = (ysum + Dd * xv) * sz;
        }
    }

    if (!P3) {
        #pragma unroll
        for (int n = 0; n < N_; ++n) {
            const size_t o = ((size_t)(b * SEG + seg) * N_ + n) * ED_ + d;
            hend[o]  = h[n];
            pprod[o] = P[n];
        }
    }
}

// Phase 2: serial combine across segments. 2048 threads (one per (b,d)).
__global__ __launch_bounds__(256)
void ssm_combine_k(const float* __restrict__ hend, const float* __restrict__ pprod,
                   float* __restrict__ hinit)
{
    const int gid = blockIdx.x * 256 + threadIdx.x;  // 0..2047
    const int b = gid >> 10, d = gid & (ED_ - 1);
    float h[N_];
    #pragma unroll
    for (int n = 0; n < N_; ++n) h[n] = 0.0f;
    for (int s = 0; s < SEG; ++s) {
        #pragma unroll
        for (int n = 0; n < N_; ++n) {
            const size_t o = ((size_t)(b * SEG + s) * N_ + n) * ED_ + d;
            hinit[o] = h[n];
            h[n] = fmaf(pprod[o], h[n], hend[o]);
        }
    }
}

// ---------------------------------------------------------------------------
extern "C" void kernel_launch(void* const* d_in, const int* in_sizes, int n_in,
                              void* d_out, int out_size, void* d_ws, size_t ws_size,
                              hipStream_t stream)
{
    const float* x      = (const float*)d_in[0];
    const float* p_Wi   = (const float*)d_in[1];
    const float* p_bi   = (const float*)d_in[2];
    const float* p_bh   = (const float*)d_in[3];
    const float* p_Wo   = (const float*)d_in[4];
    const float* p_bo   = (const float*)d_in[5];
    const float* m_norm = (const float*)d_in[6];
    const float* m_inW  = (const float*)d_in[7];
    const float* m_cw   = (const float*)d_in[8];
    const float* m_cb   = (const float*)d_in[9];
    const float* m_xpW  = (const float*)d_in[10];
    const float* m_dtW  = (const float*)d_in[11];
    const float* m_dtb  = (const float*)d_in[12];
    const float* m_Alog = (const float*)d_in[13];
    const float* m_D    = (const float*)d_in[14];
    const float* m_outW = (const float*)d_in[15];
    const float* d_Wi   = (const float*)d_in[16];
    const float* d_bi   = (const float*)d_in[17];
    const float* d_bh   = (const float*)d_in[18];
    const float* d_Wo   = (const float*)d_in[19];
    const float* d_bo   = (const float*)d_in[20];
    float* out_f = (float*)d_out;
    float* ws = (float*)d_ws;

    // workspace layout (floats); total ~24.4M floats (~97.5 MB)
    float* OUT   = ws;              // 4096x512
    float* H1    = ws + 2097152;    // 4096x512 (reused as xn, then liquid2 hidden)
    float* XZ    = ws + 4194304;    // 4096x2048
    float* XC    = ws + 12582912;   // 4096x1024
    float* DBL   = ws + 16777216;   // 4096x64
    float* DELTA = ws + 17039360;   // 4096x1024 (reused as y in-place)
    float* HEND  = ws + 21233664;   // 2*32*16*1024
    float* PPROD = ws + 22282240;
    float* HINIT = ws + 23330816;

    const dim3 blk(256);

    // liquid1: h = tanh(x@Wi + bi + bh); out = h@Wo + bo
    gemm_f32<1, true, true, false, false><<<dim3(64, 8), blk, 0, stream>>>(
        x, IN_, p_Wi, H_, p_bi, p_bh, H1, H_, M_TOK, H_, IN_);
    gemm_f32<0, true, false, false, false><<<dim3(64, 8), blk, 0, stream>>>(
        H1, H_, p_Wo, H_, p_bo, nullptr, OUT, H_, M_TOK, H_, H_);

    for (int l = 0; l < NL_; ++l) {
        const float* nw   = m_norm + l * H_;
        const float* inW  = m_inW  + (size_t)l * H_ * 2 * ED_;
        const float* cw   = m_cw   + l * ED_ * K_;
        const float* cb   = m_cb   + l * ED_;
        const float* xpW  = m_xpW  + (size_t)l * ED_ * 64;
        const float* dtW  = m_dtW  + l * DR_ * ED_;
        const float* dtb  = m_dtb  + l * ED_;
        const float* Alog = m_Alog + l * ED_ * N_;
        const float* Dv   = m_D    + l * ED_;
        const float* outW = m_outW + (size_t)l * ED_ * H_;

        rmsnorm_k<<<dim3(M_TOK), blk, 0, stream>>>(OUT, nw, H1);
        gemm_f32<0, false, false, false, false><<<dim3(64, 32), blk, 0, stream>>>(
            H1, H_, inW, 2 * ED_, nullptr, nullptr, XZ, 2 * ED_, M_TOK, 2 * ED_, H_);
        conv_silu_k<<<dim3(M_TOK * ED_ / 256), blk, 0, stream>>>(XZ, cw, cb, XC);
        gemm_f32<0, false, false, false, false><<<dim3(64, 1), blk, 0, stream>>>(
            XC, ED_, xpW, 64, nullptr, nullptr, DBL, 64, M_TOK, 64, ED_);
        gemm_f32<2, true, false, false, false><<<dim3(64, 16), blk, 0, stream>>>(
            DBL, 64, dtW, ED_, dtb, nullptr, DELTA, ED_, M_TOK, ED_, DR_);
        ssm_scan_k<false><<<dim3(256), blk, 0, stream>>>(
            DELTA, XC, DBL, nullptr, Alog, nullptr, HEND, PPROD, nullptr, nullptr);
        ssm_combine_k<<<dim3(8), blk, 0, stream>>>(HEND, PPROD, HINIT);
        ssm_scan_k<true><<<dim3(256), blk, 0, stream>>>(
            DELTA, XC, DBL, XZ, Alog, Dv, nullptr, nullptr, HINIT, DELTA);
        gemm_f32<0, false, false, true, false><<<dim3(64, 8), blk, 0, stream>>>(
            DELTA, ED_, outW, H_, nullptr, nullptr, OUT, H_, M_TOK, H_, ED_);
    }

    // liquid2 + final (out - tanh(out)) fused into last epilogue
    gemm_f32<1, true, true, false, false><<<dim3(64, 1), blk, 0, stream>>>(
        OUT, H_, d_Wi, OUT_, d_bi, d_bh, H1, OUT_, M_TOK, OUT_, H_);
    gemm_f32<0, true, false, false, true><<<dim3(64, 1), blk, 0, stream>>>(
        H1, OUT_, d_Wo, OUT_, d_bo, nullptr, out_f, OUT_, M_TOK, OUT_, OUT_);
}

// Round 2
// 552.363 us; speedup vs baseline: 1.7125x; 1.7125x over previous
//
#include <hip/hip_runtime.h>
#include <hip/hip_bf16.h>
#include <cstdint>
#include <cstddef>

// Problem constants
#define B_   2
#define L_   2048
#define IN_  128
#define H_   512
#define OUT_ 64
#define NL_  2
#define ED_  1024
#define N_   16
#define DR_  32
#define K_   4

static constexpr int M_TOK = B_ * L_;   // 4096 tokens
static constexpr int SEG   = 32;        // scan segments
static constexpr int TS    = L_ / SEG;  // 64 steps per segment

typedef __attribute__((ext_vector_type(8))) short bhalf8;   // 8 bf16 (4 VGPRs)
typedef __attribute__((ext_vector_type(4))) float floatx4;  // MFMA accumulator

// ---------------------------------------------------------------------------
// bf16 MFMA GEMM: C[M,N] = epi(A[M,K] @ B[K,N]), B supplied TRANSPOSED [N][K].
// 256 thr = 4 waves (2x2), BK=64, per-wave (BM/2)x(BN/2) of 16x16x32 frags.
// EPI: 0 plain f32, 1 C+=v (f32), 2 tanh(v+b1+b2)->bf16, 3 v+b1->f32,
//      4 split-K partial: C[kz*M*N + row*N + col] = v
// ---------------------------------------------------------------------------
template<int BM, int BN, int EPI>
__global__ __launch_bounds__(256)
void mfma_gemm(const ushort* __restrict__ A, int lda,
               const ushort* __restrict__ Bt, int ldb,
               const float* __restrict__ b1, const float* __restrict__ b2,
               float* C, __hip_bfloat16* Cb, int ldc,
               int M, int N, int kc)
{
    constexpr int BK = 64, LK = 72;  // 144B rows: 16B-aligned, ~2-way banks
    __shared__ __align__(16) ushort As[BM][LK];
    __shared__ __align__(16) ushort Bs[BN][LK];

    const int tid  = threadIdx.x;
    const int bm   = blockIdx.x * BM, bn = blockIdx.y * BN;
    const int kz   = blockIdx.z;
    const int kbeg = kz * kc;
    const int lane = tid & 63, wave = tid >> 6;
    const int wr = wave >> 1, wc = wave & 1;
    constexpr int WM = BM / 2, WN = BN / 2;
    constexpr int FM = WM / 16, FN = WN / 16;
    const int fr = lane & 15, fg = lane >> 4;
    constexpr int AL = (BM * BK) / (8 * 256);
    constexpr int BL = (BN * BK) / (8 * 256);

    floatx4 acc[FM][FN] = {};

    for (int k0 = kbeg; k0 < kbeg + kc; k0 += BK) {
        #pragma unroll
        for (int i = 0; i < AL; ++i) {
            int lin = tid + i * 256;
            int r = lin >> 3, c = (lin & 7) * 8;
            *reinterpret_cast<bhalf8*>(&As[r][c]) =
                *reinterpret_cast<const bhalf8*>(&A[(size_t)(bm + r) * lda + k0 + c]);
        }
        #pragma unroll
        for (int i = 0; i < BL; ++i) {
            int lin = tid + i * 256;
            int r = lin >> 3, c = (lin & 7) * 8;
            *reinterpret_cast<bhalf8*>(&Bs[r][c]) =
                *reinterpret_cast<const bhalf8*>(&Bt[(size_t)(bn + r) * ldb + k0 + c]);
        }
        __syncthreads();
        #pragma unroll
        for (int kk = 0; kk < BK; kk += 32) {
            bhalf8 fa[FM], fb[FN];
            #pragma unroll
            for (int m = 0; m < FM; ++m)
                fa[m] = *reinterpret_cast<const bhalf8*>(&As[wr * WM + m * 16 + fr][kk + fg * 8]);
            #pragma unroll
            for (int n = 0; n < FN; ++n)
                fb[n] = *reinterpret_cast<const bhalf8*>(&Bs[wc * WN + n * 16 + fr][kk + fg * 8]);
            #pragma unroll
            for (int m = 0; m < FM; ++m)
                #pragma unroll
                for (int n = 0; n < FN; ++n)
                    acc[m][n] = __builtin_amdgcn_mfma_f32_16x16x32_bf16(
                        fa[m], fb[n], acc[m][n], 0, 0, 0);
        }
        __syncthreads();
    }

    #pragma unroll
    for (int m = 0; m < FM; ++m) {
        #pragma unroll
        for (int n = 0; n < FN; ++n) {
            const int row0 = bm + wr * WM + m * 16 + fg * 4;
            const int col  = bn + wc * WN + n * 16 + fr;
            #pragma unroll
            for (int r = 0; r < 4; ++r) {
                float v = acc[m][n][r];
                const int row = row0 + r;
                if (EPI == 0) {
                    C[(size_t)row * ldc + col] = v;
                } else if (EPI == 1) {
                    C[(size_t)row * ldc + col] += v;
                } else if (EPI == 2) {
                    Cb[(size_t)row * ldc + col] =
                        __float2bfloat16(tanhf(v + b1[col] + b2[col]));
                } else if (EPI == 3) {
                    C[(size_t)row * ldc + col] = v + b1[col];
                } else if (EPI == 4) {
                    C[(size_t)kz * M * N + (size_t)row * N + col] = v;
                }
            }
        }
    }
}

// split-K reduce (+ optional bias/tanh)
template<int NP, int ACT, bool B1, bool B2>
__global__ __launch_bounds__(256)
void reduce_part_k(const float* __restrict__ P, const float* __restrict__ b1,
                   const float* __restrict__ b2, float* __restrict__ O,
                   int MN, int Ncols)
{
    const int i = blockIdx.x * 256 + threadIdx.x;
    float s = 0.0f;
    #pragma unroll
    for (int z = 0; z < NP; ++z) s += P[(size_t)z * MN + i];
    const int col = i & (Ncols - 1);
    if (B1) s += b1[col];
    if (B2) s += b2[col];
    if (ACT == 1) s = tanhf(s);
    O[i] = s;
}

// f32 [K][N] -> bf16 [N][K] transpose-convert (32x32 LDS tile)
__global__ __launch_bounds__(256)
void transpose_bf16_k(const float* __restrict__ W, __hip_bfloat16* __restrict__ Wt,
                      int K, int N)
{
    __shared__ float t[32][33];
    const int k0 = blockIdx.x * 32, n0 = blockIdx.y * 32;
    const int c = threadIdx.x & 31, r4 = threadIdx.x >> 5;
    #pragma unroll
    for (int i = 0; i < 4; ++i) {
        int r = r4 + i * 8;
        t[r][c] = W[(size_t)(k0 + r) * N + n0 + c];
    }
    __syncthreads();
    #pragma unroll
    for (int i = 0; i < 4; ++i) {
        int r = r4 + i * 8;
        Wt[(size_t)(n0 + r) * K + k0 + c] = __float2bfloat16(t[c][r]);
    }
}

__global__ __launch_bounds__(256)
void cvt_bf16_k(const float* __restrict__ in, __hip_bfloat16* __restrict__ out, int n)
{
    const int i = blockIdx.x * 256 + threadIdx.x;
    if (i < n) out[i] = __float2bfloat16(in[i]);
}

// ---------------------------------------------------------------------------
// f32 SIMT GEMM (kept for the small dt / final GEMMs)
// ---------------------------------------------------------------------------
template<int ACT, bool BIAS1, bool BIAS2, bool RES, bool FINALSUB>
__global__ __launch_bounds__(256)
void gemm_f32(const float* __restrict__ A, int lda,
              const float* __restrict__ W, int ldw,
              const float* __restrict__ b1, const float* __restrict__ b2,
              float* C, int ldc, int M, int N, int K)
{
    __shared__ __align__(16) float As[16][68];
    __shared__ __align__(16) float Ws[16][68];

    const int tid = threadIdx.x;
    const int bm = blockIdx.x * 64;
    const int bn = blockIdx.y * 64;
    const int tx = tid & 15, ty = tid >> 4;
    const int ar  = tid >> 2;
    const int acq = (tid & 3) * 4;
    const int wr  = tid >> 4;
    const int wc  = (tid & 15) * 4;

    float acc[4][4] = {};

    for (int k0 = 0; k0 < K; k0 += 16) {
        float4 av4 = *reinterpret_cast<const float4*>(&A[(size_t)(bm + ar) * lda + k0 + acq]);
        float4 wv4 = *reinterpret_cast<const float4*>(&W[(size_t)(k0 + wr) * ldw + bn + wc]);
        As[acq + 0][ar] = av4.x;
        As[acq + 1][ar] = av4.y;
        As[acq + 2][ar] = av4.z;
        As[acq + 3][ar] = av4.w;
        *reinterpret_cast<float4*>(&Ws[wr][wc]) = wv4;
        __syncthreads();
        #pragma unroll
        for (int kk = 0; kk < 16; ++kk) {
            float4 a = *reinterpret_cast<const float4*>(&As[kk][ty * 4]);
            float4 b = *reinterpret_cast<const float4*>(&Ws[kk][tx * 4]);
            float aa[4] = {a.x, a.y, a.z, a.w};
            float bb[4] = {b.x, b.y, b.z, b.w};
            #pragma unroll
            for (int i = 0; i < 4; ++i)
                #pragma unroll
                for (int j = 0; j < 4; ++j)
                    acc[i][j] = fmaf(aa[i], bb[j], acc[i][j]);
        }
        __syncthreads();
    }

    #pragma unroll
    for (int i = 0; i < 4; ++i) {
        const int row = bm + ty * 4 + i;
        #pragma unroll
        for (int j = 0; j < 4; ++j) {
            const int col = bn + tx * 4 + j;
            float v = acc[i][j];
            if (BIAS1) v += b1[col];
            if (BIAS2) v += b2[col];
            if (ACT == 1) v = tanhf(v);
            if (ACT == 2) v = fmaxf(v, 0.0f) + log1pf(expf(-fabsf(v)));
            float* cp = C + (size_t)row * ldc + col;
            if (RES) v += *cp;
            if (FINALSUB) v = v - tanhf(v);
            *cp = v;
        }
    }
}

// ---------------------------------------------------------------------------
// RMSNorm over H=512 -> bf16 out
// ---------------------------------------------------------------------------
__global__ __launch_bounds__(256)
void rmsnorm_k(const float* __restrict__ x, const float* __restrict__ w,
               __hip_bfloat16* __restrict__ o)
{
    const int row = blockIdx.x;
    const int tid = threadIdx.x;
    const float* xr = x + (size_t)row * H_;
    float v0 = xr[tid], v1 = xr[tid + 256];
    float s = v0 * v0 + v1 * v1;
    #pragma unroll
    for (int off = 32; off > 0; off >>= 1) s += __shfl_down(s, off, 64);
    __shared__ float ps[4];
    __shared__ float scale_s;
    const int wave = tid >> 6, lane = tid & 63;
    if (lane == 0) ps[wave] = s;
    __syncthreads();
    if (tid == 0) {
        float tot = ps[0] + ps[1] + ps[2] + ps[3];
        scale_s = rsqrtf(tot * (1.0f / H_) + 1e-5f);
    }
    __syncthreads();
    const float sc = scale_s;
    o[(size_t)row * H_ + tid]       = __float2bfloat16(v0 * sc * w[tid]);
    o[(size_t)row * H_ + tid + 256] = __float2bfloat16(v1 * sc * w[tid + 256]);
}

// ---------------------------------------------------------------------------
// Depthwise causal conv (K=4) + SiLU; writes f32 (for scan) + bf16 (for GEMM)
// ---------------------------------------------------------------------------
__global__ __launch_bounds__(256)
void conv_silu_k(const float* __restrict__ xz, const float* __restrict__ cw,
                 const float* __restrict__ cb, float* __restrict__ xc,
                 __hip_bfloat16* __restrict__ xcb)
{
    const int idx = blockIdx.x * 256 + threadIdx.x;
    const int d = idx & (ED_ - 1);
    const int t = (idx >> 10) & (L_ - 1);
    const int b = idx >> 21;
    const size_t base = (size_t)(b * L_ + t) * (2 * ED_) + d;
    float4 w = *reinterpret_cast<const float4*>(&cw[d * 4]);
    float acc = cb[d];
    acc += w.w * xz[base];
    if (t >= 1) acc += w.z * xz[base - 1 * 2 * ED_];
    if (t >= 2) acc += w.y * xz[base - 2 * 2 * ED_];
    if (t >= 3) acc += w.x * xz[base - 3 * 2 * ED_];
    const float s = acc / (1.0f + expf(-acc));
    xc[(size_t)(b * L_ + t) * ED_ + d] = s;
    xcb[(size_t)(b * L_ + t) * ED_ + d] = __float2bfloat16(s);
}

// ---------------------------------------------------------------------------
// SSM chunked scan (phase1 / phase3); phase3 emits bf16 y
// ---------------------------------------------------------------------------
template<bool P3>
__global__ __launch_bounds__(256)
void ssm_scan_k(const float* __restrict__ delta,
                const float* __restrict__ xc,
                const float* __restrict__ dbl,
                const float* __restrict__ xz,
                const float* __restrict__ A_log,
                const float* __restrict__ Dv,
                float* __restrict__ hend, float* __restrict__ pprod,
                const float* __restrict__ hinit,
                __hip_bfloat16* __restrict__ ybuf)
{
    __shared__ float bc[TS][32];
    const int bx   = blockIdx.x;
    const int seg  = bx & (SEG - 1);
    const int dblk = (bx >> 5) & 3;
    const int b    = bx >> 7;
    const int tid  = threadIdx.x;
    const int d    = dblk * 256 + tid;
    const int t0   = seg * TS;

    #pragma unroll
    for (int e = 0; e < (TS * 32) / 256; ++e) {
        int lin = tid + e * 256;
        int tr = lin >> 5, j = lin & 31;
        bc[tr][j] = dbl[(size_t)(b * L_ + t0 + tr) * 64 + 32 + j];
    }
    __syncthreads();

    float Av[N_];
    #pragma unroll
    for (int n = 0; n < N_; ++n) Av[n] = -expf(A_log[d * N_ + n]);

    float h[N_], P[N_];
    if (P3) {
        #pragma unroll
        for (int n = 0; n < N_; ++n)
            h[n] = hinit[((size_t)(b * SEG + seg) * N_ + n) * ED_ + d];
    } else {
        #pragma unroll
        for (int n = 0; n < N_; ++n) { h[n] = 0.0f; P[n] = 1.0f; }
    }
    float Dd = 0.0f;
    if (P3) Dd = Dv[d];

    for (int tt = 0; tt < TS; ++tt) {
        const size_t row = (size_t)(b * L_ + t0 + tt);
        const float dv = delta[row * ED_ + d];
        const float xv = xc[row * ED_ + d];
        const float dx = dv * xv;
        float ysum = 0.0f;
        #pragma unroll
        for (int n = 0; n < N_; ++n) {
            const float dA = expf(dv * Av[n]);
            h[n] = fmaf(dA, h[n], dx * bc[tt][n]);
            if (!P3) P[n] *= dA;
            else     ysum = fmaf(h[n], bc[tt][16 + n], ysum);
        }
        if (P3) {
            const float zv = xz[row * (2 * ED_) + ED_ + d];
            const float sz = zv / (1.0f + expf(-zv));
            ybuf[row * ED_ + d] = __float2bfloat16((ysum + Dd * xv) * sz);
        }
    }

    if (!P3) {
        #pragma unroll
        for (int n = 0; n < N_; ++n) {
            const size_t o = ((size_t)(b * SEG + seg) * N_ + n) * ED_ + d;
            hend[o]  = h[n];
            pprod[o] = P[n];
        }
    }
}

__global__ __launch_bounds__(256)
void ssm_combine_k(const float* __restrict__ hend, const float* __restrict__ pprod,
                   float* __restrict__ hinit)
{
    const int gid = blockIdx.x * 256 + threadIdx.x;
    const int b = gid >> 10, d = gid & (ED_ - 1);
    float h[N_];
    #pragma unroll
    for (int n = 0; n < N_; ++n) h[n] = 0.0f;
    for (int s = 0; s < SEG; ++s) {
        #pragma unroll
        for (int n = 0; n < N_; ++n) {
            const size_t o = ((size_t)(b * SEG + s) * N_ + n) * ED_ + d;
            hinit[o] = h[n];
            h[n] = fmaf(pprod[o], h[n], hend[o]);
        }
    }
}

// ---------------------------------------------------------------------------
extern "C" void kernel_launch(void* const* d_in, const int* in_sizes, int n_in,
                              void* d_out, int out_size, void* d_ws, size_t ws_size,
                              hipStream_t stream)
{
    const float* x      = (const float*)d_in[0];
    const float* p_Wi   = (const float*)d_in[1];
    const float* p_bi   = (const float*)d_in[2];
    const float* p_bh   = (const float*)d_in[3];
    const float* p_Wo   = (const float*)d_in[4];
    const float* p_bo   = (const float*)d_in[5];
    const float* m_norm = (const float*)d_in[6];
    const float* m_inW  = (const float*)d_in[7];
    const float* m_cw   = (const float*)d_in[8];
    const float* m_cb   = (const float*)d_in[9];
    const float* m_xpW  = (const float*)d_in[10];
    const float* m_dtW  = (const float*)d_in[11];
    const float* m_dtb  = (const float*)d_in[12];
    const float* m_Alog = (const float*)d_in[13];
    const float* m_D    = (const float*)d_in[14];
    const float* m_outW = (const float*)d_in[15];
    const float* d_Wi   = (const float*)d_in[16];
    const float* d_bi   = (const float*)d_in[17];
    const float* d_bh   = (const float*)d_in[18];
    const float* d_Wo   = (const float*)d_in[19];
    const float* d_bo   = (const float*)d_in[20];
    float* out_f = (float*)d_out;
    float* ws = (float*)d_ws;

    // ---- workspace layout (floats) ----
    float* OUT   = ws;                 // 2,097,152
    float* XZ    = ws + 2097152;       // 8,388,608
    float* XC    = ws + 10485760;      // 4,194,304
    float* DBL   = ws + 14680064;      // 262,144
    float* DELTA = ws + 14942208;      // 4,194,304 (also hosts xproj split-K partials)
    float* R     = ws + 19136512;      // 3,145,728 multi-use region
    float* WT    = ws + 22282240;      // 1,818,624 (bf16 transposed weights)
    // total 24,100,864 floats = 96.4 MB

    // R aliases
    __hip_bfloat16* Xb    = (__hip_bfloat16*)R;                  // 4096x128
    __hip_bfloat16* H1b   = (__hip_bfloat16*)(R + 262144);       // 4096x512
    __hip_bfloat16* XNb   = (__hip_bfloat16*)R;                  // 4096x512
    __hip_bfloat16* XCb   = (__hip_bfloat16*)R;                  // 4096x1024
    float* HEND  = R;                                            // 1,048,576
    float* PPROD = R + 1048576;                                  // 1,048,576
    float* HINIT = R + 2097152;                                  // 1,048,576
    __hip_bfloat16* YB    = (__hip_bfloat16*)R;                  // 4096x1024
    float* CPART2 = R;                                           // 8 x 262,144
    __hip_bfloat16* OUTb  = (__hip_bfloat16*)(R + 2097152);      // 4096x512
    float* H2    = R;                                            // 262,144 (aliases CPART2 z=0; safe)
    float* CPARTX = DELTA;                                       // 8 x 262,144

    // transposed bf16 weights
    __hip_bfloat16* WTu     = (__hip_bfloat16*)WT;
    __hip_bfloat16* T_pWi   = WTu;            // [512][128]
    __hip_bfloat16* T_pWo   = WTu + 65536;    // [512][512]
    __hip_bfloat16* T_inW0  = WTu + 327680;   // [2048][512]
    __hip_bfloat16* T_inW1  = WTu + 1376256;
    __hip_bfloat16* T_xpW0  = WTu + 2424832;  // [64][1024]
    __hip_bfloat16* T_xpW1  = WTu + 2490368;
    __hip_bfloat16* T_outW0 = WTu + 2555904;  // [512][1024]
    __hip_bfloat16* T_outW1 = WTu + 3080192;
    __hip_bfloat16* T_dWi   = WTu + 3604480;  // [64][512]

    const dim3 blk(256);

    // ---- weight conversions ----
    cvt_bf16_k<<<dim3(2048), blk, 0, stream>>>(x, Xb, M_TOK * IN_);
    transpose_bf16_k<<<dim3(4, 16), blk, 0, stream>>>(p_Wi, T_pWi, IN_, H_);
    transpose_bf16_k<<<dim3(16, 16), blk, 0, stream>>>(p_Wo, T_pWo, H_, H_);
    transpose_bf16_k<<<dim3(16, 64), blk, 0, stream>>>(m_inW, T_inW0, H_, 2 * ED_);
    transpose_bf16_k<<<dim3(16, 64), blk, 0, stream>>>(m_inW + (size_t)H_ * 2 * ED_, T_inW1, H_, 2 * ED_);
    transpose_bf16_k<<<dim3(32, 2), blk, 0, stream>>>(m_xpW, T_xpW0, ED_, 64);
    transpose_bf16_k<<<dim3(32, 2), blk, 0, stream>>>(m_xpW + (size_t)ED_ * 64, T_xpW1, ED_, 64);
    transpose_bf16_k<<<dim3(32, 16), blk, 0, stream>>>(m_outW, T_outW0, ED_, H_);
    transpose_bf16_k<<<dim3(32, 16), blk, 0, stream>>>(m_outW + (size_t)ED_ * H_, T_outW1, ED_, H_);
    transpose_bf16_k<<<dim3(16, 2), blk, 0, stream>>>(d_Wi, T_dWi, H_, OUT_);

    // ---- liquid1 ----
    mfma_gemm<128, 64, 2><<<dim3(32, 8), blk, 0, stream>>>(
        (const ushort*)Xb, IN_, (const ushort*)T_pWi, IN_, p_bi, p_bh,
        nullptr, H1b, H_, M_TOK, H_, IN_);
    mfma_gemm<128, 64, 3><<<dim3(32, 8), blk, 0, stream>>>(
        (const ushort*)H1b, H_, (const ushort*)T_pWo, H_, p_bo, nullptr,
        OUT, nullptr, H_, M_TOK, H_, H_);

    for (int l = 0; l < NL_; ++l) {
        const float* nw   = m_norm + l * H_;
        const float* cw   = m_cw   + l * ED_ * K_;
        const float* cb   = m_cb   + l * ED_;
        const float* dtW  = m_dtW  + l * DR_ * ED_;
        const float* dtb  = m_dtb  + l * ED_;
        const float* Alog = m_Alog + l * ED_ * N_;
        const float* Dv   = m_D    + l * ED_;
        const __hip_bfloat16* TinW  = l ? T_inW1  : T_inW0;
        const __hip_bfloat16* TxpW  = l ? T_xpW1  : T_xpW0;
        const __hip_bfloat16* ToutW = l ? T_outW1 : T_outW0;

        rmsnorm_k<<<dim3(M_TOK), blk, 0, stream>>>(OUT, nw, XNb);
        mfma_gemm<128, 128, 0><<<dim3(32, 16), blk, 0, stream>>>(
            (const ushort*)XNb, H_, (const ushort*)TinW, H_, nullptr, nullptr,
            XZ, nullptr, 2 * ED_, M_TOK, 2 * ED_, H_);
        conv_silu_k<<<dim3(M_TOK * ED_ / 256), blk, 0, stream>>>(XZ, cw, cb, XC, XCb);
        mfma_gemm<128, 64, 4><<<dim3(32, 1, 8), blk, 0, stream>>>(
            (const ushort*)XCb, ED_, (const ushort*)TxpW, ED_, nullptr, nullptr,
            CPARTX, nullptr, 64, M_TOK, 64, ED_ / 8);
        reduce_part_k<8, 0, false, false><<<dim3(1024), blk, 0, stream>>>(
            CPARTX, nullptr, nullptr, DBL, M_TOK * 64, 64);
        gemm_f32<2, true, false, false, false><<<dim3(64, 16), blk, 0, stream>>>(
            DBL, 64, dtW, ED_, dtb, nullptr, DELTA, ED_, M_TOK, ED_, DR_);
        ssm_scan_k<false><<<dim3(256), blk, 0, stream>>>(
            DELTA, XC, DBL, nullptr, Alog, nullptr, HEND, PPROD, nullptr, nullptr);
        ssm_combine_k<<<dim3(8), blk, 0, stream>>>(HEND, PPROD, HINIT);
        ssm_scan_k<true><<<dim3(256), blk, 0, stream>>>(
            DELTA, XC, DBL, XZ, Alog, Dv, nullptr, nullptr, HINIT, YB);
        mfma_gemm<128, 64, 1><<<dim3(32, 8), blk, 0, stream>>>(
            (const ushort*)YB, ED_, (const ushort*)ToutW, ED_, nullptr, nullptr,
            OUT, nullptr, H_, M_TOK, H_, ED_);
    }

    // ---- liquid2 + final ----
    cvt_bf16_k<<<dim3(8192), blk, 0, stream>>>(OUT, OUTb, M_TOK * H_);
    mfma_gemm<128, 64, 4><<<dim3(32, 1, 8), blk, 0, stream>>>(
        (const ushort*)OUTb, H_, (const ushort*)T_dWi, H_, nullptr, nullptr,
        CPART2, nullptr, 64, M_TOK, 64, H_ / 8);
    reduce_part_k<8, 1, true, true><<<dim3(1024), blk, 0, stream>>>(
        CPART2, d_bi, d_bh, H2, M_TOK * 64, 64);
    gemm_f32<0, true, false, false, true><<<dim3(64, 1), blk, 0, stream>>>(
        H2, 64, d_Wo, 64, d_bo, nullptr, out_f, 64, M_TOK, 64, 64);
}

// Round 3
// 455.240 us; speedup vs baseline: 2.0779x; 1.2133x over previous
//
#include <hip/hip_runtime.h>
#include <hip/hip_bf16.h>
#include <cstdint>
#include <cstddef>

// Problem constants
#define B_   2
#define L_   2048
#define IN_  128
#define H_   512
#define OUT_ 64
#define NL_  2
#define ED_  1024
#define N_   16
#define DR_  32
#define K_   4

static constexpr int M_TOK = B_ * L_;   // 4096 tokens
static constexpr int SEG   = 64;        // scan segments
static constexpr int TS    = L_ / SEG;  // 32 steps per segment

typedef __attribute__((ext_vector_type(8))) short bhalf8;   // 8 bf16 (4 VGPRs)
typedef __attribute__((ext_vector_type(4))) float floatx4;  // MFMA accumulator

// ---------------------------------------------------------------------------
// bf16 MFMA GEMM: C[M,N] = epi(A[M,K] @ B[K,N]), B supplied TRANSPOSED [N][K].
// 256 thr = 4 waves (2x2), BK=64, per-wave (BM/2)x(BN/2) of 16x16x32 frags.
// EPI: 0 plain f32, 1 C+=v (f32), 2 tanh(v+b1+b2)->bf16, 3 v+b1->f32,
//      4 split-K partial: C[kz*M*N + row*N + col] = v
// ---------------------------------------------------------------------------
template<int BM, int BN, int EPI>
__global__ __launch_bounds__(256)
void mfma_gemm(const ushort* __restrict__ A, int lda,
               const ushort* __restrict__ Bt, int ldb,
               const float* __restrict__ b1, const float* __restrict__ b2,
               float* C, __hip_bfloat16* Cb, int ldc,
               int M, int N, int kc)
{
    constexpr int BK = 64, LK = 72;  // 144B rows: 16B-aligned, ~2-way banks
    __shared__ __align__(16) ushort As[BM][LK];
    __shared__ __align__(16) ushort Bs[BN][LK];

    const int tid  = threadIdx.x;
    const int bm   = blockIdx.x * BM, bn = blockIdx.y * BN;
    const int kz   = blockIdx.z;
    const int kbeg = kz * kc;
    const int lane = tid & 63, wave = tid >> 6;
    const int wr = wave >> 1, wc = wave & 1;
    constexpr int WM = BM / 2, WN = BN / 2;
    constexpr int FM = WM / 16, FN = WN / 16;
    const int fr = lane & 15, fg = lane >> 4;
    constexpr int AL = (BM * BK) / (8 * 256);
    constexpr int BL = (BN * BK) / (8 * 256);

    floatx4 acc[FM][FN] = {};

    for (int k0 = kbeg; k0 < kbeg + kc; k0 += BK) {
        #pragma unroll
        for (int i = 0; i < AL; ++i) {
            int lin = tid + i * 256;
            int r = lin >> 3, c = (lin & 7) * 8;
            *reinterpret_cast<bhalf8*>(&As[r][c]) =
                *reinterpret_cast<const bhalf8*>(&A[(size_t)(bm + r) * lda + k0 + c]);
        }
        #pragma unroll
        for (int i = 0; i < BL; ++i) {
            int lin = tid + i * 256;
            int r = lin >> 3, c = (lin & 7) * 8;
            *reinterpret_cast<bhalf8*>(&Bs[r][c]) =
                *reinterpret_cast<const bhalf8*>(&Bt[(size_t)(bn + r) * ldb + k0 + c]);
        }
        __syncthreads();
        #pragma unroll
        for (int kk = 0; kk < BK; kk += 32) {
            bhalf8 fa[FM], fb[FN];
            #pragma unroll
            for (int m = 0; m < FM; ++m)
                fa[m] = *reinterpret_cast<const bhalf8*>(&As[wr * WM + m * 16 + fr][kk + fg * 8]);
            #pragma unroll
            for (int n = 0; n < FN; ++n)
                fb[n] = *reinterpret_cast<const bhalf8*>(&Bs[wc * WN + n * 16 + fr][kk + fg * 8]);
            #pragma unroll
            for (int m = 0; m < FM; ++m)
                #pragma unroll
                for (int n = 0; n < FN; ++n)
                    acc[m][n] = __builtin_amdgcn_mfma_f32_16x16x32_bf16(
                        fa[m], fb[n], acc[m][n], 0, 0, 0);
        }
        __syncthreads();
    }

    #pragma unroll
    for (int m = 0; m < FM; ++m) {
        #pragma unroll
        for (int n = 0; n < FN; ++n) {
            const int row0 = bm + wr * WM + m * 16 + fg * 4;
            const int col  = bn + wc * WN + n * 16 + fr;
            #pragma unroll
            for (int r = 0; r < 4; ++r) {
                float v = acc[m][n][r];
                const int row = row0 + r;
                if (EPI == 0) {
                    C[(size_t)row * ldc + col] = v;
                } else if (EPI == 1) {
                    C[(size_t)row * ldc + col] += v;
                } else if (EPI == 2) {
                    Cb[(size_t)row * ldc + col] =
                        __float2bfloat16(tanhf(v + b1[col] + b2[col]));
                } else if (EPI == 3) {
                    C[(size_t)row * ldc + col] = v + b1[col];
                } else if (EPI == 4) {
                    C[(size_t)kz * M * N + (size_t)row * N + col] = v;
                }
            }
        }
    }
}

// split-K reduce (+ optional bias/tanh)
template<int NP, int ACT, bool B1, bool B2>
__global__ __launch_bounds__(256)
void reduce_part_k(const float* __restrict__ P, const float* __restrict__ b1,
                   const float* __restrict__ b2, float* __restrict__ O,
                   int MN, int Ncols)
{
    const int i = blockIdx.x * 256 + threadIdx.x;
    float s = 0.0f;
    #pragma unroll
    for (int z = 0; z < NP; ++z) s += P[(size_t)z * MN + i];
    const int col = i & (Ncols - 1);
    if (B1) s += b1[col];
    if (B2) s += b2[col];
    if (ACT == 1) s = tanhf(s);
    O[i] = s;
}

// f32 [K][N] -> bf16 [N][K] transpose-convert (32x32 LDS tile)
__global__ __launch_bounds__(256)
void transpose_bf16_k(const float* __restrict__ W, __hip_bfloat16* __restrict__ Wt,
                      int K, int N)
{
    __shared__ float t[32][33];
    const int k0 = blockIdx.x * 32, n0 = blockIdx.y * 32;
    const int c = threadIdx.x & 31, r4 = threadIdx.x >> 5;
    #pragma unroll
    for (int i = 0; i < 4; ++i) {
        int r = r4 + i * 8;
        t[r][c] = W[(size_t)(k0 + r) * N + n0 + c];
    }
    __syncthreads();
    #pragma unroll
    for (int i = 0; i < 4; ++i) {
        int r = r4 + i * 8;
        Wt[(size_t)(n0 + r) * K + k0 + c] = __float2bfloat16(t[c][r]);
    }
}

__global__ __launch_bounds__(256)
void cvt_bf16_k(const float* __restrict__ in, __hip_bfloat16* __restrict__ out, int n)
{
    const int i = blockIdx.x * 256 + threadIdx.x;
    if (i < n) out[i] = __float2bfloat16(in[i]);
}

// ---------------------------------------------------------------------------
// f32 SIMT GEMM (kept for the small dt / final GEMMs)
// ---------------------------------------------------------------------------
template<int ACT, bool BIAS1, bool BIAS2, bool RES, bool FINALSUB>
__global__ __launch_bounds__(256)
void gemm_f32(const float* __restrict__ A, int lda,
              const float* __restrict__ W, int ldw,
              const float* __restrict__ b1, const float* __restrict__ b2,
              float* C, int ldc, int M, int N, int K)
{
    __shared__ __align__(16) float As[16][68];
    __shared__ __align__(16) float Ws[16][68];

    const int tid = threadIdx.x;
    const int bm = blockIdx.x * 64;
    const int bn = blockIdx.y * 64;
    const int tx = tid & 15, ty = tid >> 4;
    const int ar  = tid >> 2;
    const int acq = (tid & 3) * 4;
    const int wr  = tid >> 4;
    const int wc  = (tid & 15) * 4;

    float acc[4][4] = {};

    for (int k0 = 0; k0 < K; k0 += 16) {
        float4 av4 = *reinterpret_cast<const float4*>(&A[(size_t)(bm + ar) * lda + k0 + acq]);
        float4 wv4 = *reinterpret_cast<const float4*>(&W[(size_t)(k0 + wr) * ldw + bn + wc]);
        As[acq + 0][ar] = av4.x;
        As[acq + 1][ar] = av4.y;
        As[acq + 2][ar] = av4.z;
        As[acq + 3][ar] = av4.w;
        *reinterpret_cast<float4*>(&Ws[wr][wc]) = wv4;
        __syncthreads();
        #pragma unroll
        for (int kk = 0; kk < 16; ++kk) {
            float4 a = *reinterpret_cast<const float4*>(&As[kk][ty * 4]);
            float4 b = *reinterpret_cast<const float4*>(&Ws[kk][tx * 4]);
            float aa[4] = {a.x, a.y, a.z, a.w};
            float bb[4] = {b.x, b.y, b.z, b.w};
            #pragma unroll
            for (int i = 0; i < 4; ++i)
                #pragma unroll
                for (int j = 0; j < 4; ++j)
                    acc[i][j] = fmaf(aa[i], bb[j], acc[i][j]);
        }
        __syncthreads();
    }

    #pragma unroll
    for (int i = 0; i < 4; ++i) {
        const int row = bm + ty * 4 + i;
        #pragma unroll
        for (int j = 0; j < 4; ++j) {
            const int col = bn + tx * 4 + j;
            float v = acc[i][j];
            if (BIAS1) v += b1[col];
            if (BIAS2) v += b2[col];
            if (ACT == 1) v = tanhf(v);
            if (ACT == 2) v = fmaxf(v, 0.0f) + log1pf(expf(-fabsf(v)));
            float* cp = C + (size_t)row * ldc + col;
            if (RES) v += *cp;
            if (FINALSUB) v = v - tanhf(v);
            *cp = v;
        }
    }
}

// ---------------------------------------------------------------------------
// RMSNorm over H=512 -> bf16 out
// ---------------------------------------------------------------------------
__global__ __launch_bounds__(256)
void rmsnorm_k(const float* __restrict__ x, const float* __restrict__ w,
               __hip_bfloat16* __restrict__ o)
{
    const int row = blockIdx.x;
    const int tid = threadIdx.x;
    const float* xr = x + (size_t)row * H_;
    float v0 = xr[tid], v1 = xr[tid + 256];
    float s = v0 * v0 + v1 * v1;
    #pragma unroll
    for (int off = 32; off > 0; off >>= 1) s += __shfl_down(s, off, 64);
    __shared__ float ps[4];
    __shared__ float scale_s;
    const int wave = tid >> 6, lane = tid & 63;
    if (lane == 0) ps[wave] = s;
    __syncthreads();
    if (tid == 0) {
        float tot = ps[0] + ps[1] + ps[2] + ps[3];
        scale_s = rsqrtf(tot * (1.0f / H_) + 1e-5f);
    }
    __syncthreads();
    const float sc = scale_s;
    o[(size_t)row * H_ + tid]       = __float2bfloat16(v0 * sc * w[tid]);
    o[(size_t)row * H_ + tid + 256] = __float2bfloat16(v1 * sc * w[tid + 256]);
}

// ---------------------------------------------------------------------------
// Depthwise causal conv (K=4) + SiLU; reads de-interleaved XCR (M_TOK x ED)
// ---------------------------------------------------------------------------
__global__ __launch_bounds__(256)
void conv_silu_k(const float* __restrict__ xcr, const float* __restrict__ cw,
                 const float* __restrict__ cb, float* __restrict__ xc,
                 __hip_bfloat16* __restrict__ xcb)
{
    const int idx = blockIdx.x * 256 + threadIdx.x;
    const int d = idx & (ED_ - 1);
    const int t = (idx >> 10) & (L_ - 1);
    const int b = idx >> 21;
    const size_t base = (size_t)(b * L_ + t) * ED_ + d;
    float4 w = *reinterpret_cast<const float4*>(&cw[d * 4]);
    float acc = cb[d];
    acc += w.w * xcr[base];
    if (t >= 1) acc += w.z * xcr[base - 1 * ED_];
    if (t >= 2) acc += w.y * xcr[base - 2 * ED_];
    if (t >= 3) acc += w.x * xcr[base - 3 * ED_];
    const float s = acc / (1.0f + expf(-acc));
    xc[base] = s;
    xcb[base] = __float2bfloat16(s);
}

// ---------------------------------------------------------------------------
// SSM chunked scan (phase1 / phase3); phase3 emits bf16 y. SEG=64, TS=32.
// grid: B*SEG*(ED/256) = 512 blocks.
// ---------------------------------------------------------------------------
template<bool P3>
__global__ __launch_bounds__(256)
void ssm_scan_k(const float* __restrict__ delta,
                const float* __restrict__ xc,
                const float* __restrict__ dbl,
                const float* __restrict__ zbuf,
                const float* __restrict__ A_log,
                const float* __restrict__ Dv,
                float* __restrict__ hend, float* __restrict__ pprod,
                const float* __restrict__ hinit,
                __hip_bfloat16* __restrict__ ybuf)
{
    __shared__ float bc[TS][32];
    const int bx   = blockIdx.x;
    const int seg  = bx & (SEG - 1);
    const int dblk = (bx >> 6) & 3;
    const int b    = bx >> 8;
    const int tid  = threadIdx.x;
    const int d    = dblk * 256 + tid;
    const int t0   = seg * TS;

    #pragma unroll
    for (int e = 0; e < (TS * 32) / 256; ++e) {
        int lin = tid + e * 256;
        int tr = lin >> 5, j = lin & 31;
        bc[tr][j] = dbl[(size_t)(b * L_ + t0 + tr) * 64 + 32 + j];
    }
    __syncthreads();

    float Av[N_];
    #pragma unroll
    for (int n = 0; n < N_; ++n) Av[n] = -expf(A_log[d * N_ + n]);

    float h[N_], P[N_];
    if (P3) {
        #pragma unroll
        for (int n = 0; n < N_; ++n)
            h[n] = hinit[((size_t)(b * SEG + seg) * N_ + n) * ED_ + d];
    } else {
        #pragma unroll
        for (int n = 0; n < N_; ++n) { h[n] = 0.0f; P[n] = 1.0f; }
    }
    float Dd = 0.0f;
    if (P3) Dd = Dv[d];

    #pragma unroll 4
    for (int tt = 0; tt < TS; ++tt) {
        const size_t row = (size_t)(b * L_ + t0 + tt);
        const float dv = delta[row * ED_ + d];
        const float xv = xc[row * ED_ + d];
        const float dx = dv * xv;
        float ysum = 0.0f;
        #pragma unroll
        for (int n = 0; n < N_; ++n) {
            const float dA = expf(dv * Av[n]);
            h[n] = fmaf(dA, h[n], dx * bc[tt][n]);
            if (!P3) P[n] *= dA;
            else     ysum = fmaf(h[n], bc[tt][16 + n], ysum);
        }
        if (P3) {
            const float zv = zbuf[row * ED_ + d];
            const float sz = zv / (1.0f + expf(-zv));
            ybuf[row * ED_ + d] = __float2bfloat16((ysum + Dd * xv) * sz);
        }
    }

    if (!P3) {
        #pragma unroll
        for (int n = 0; n < N_; ++n) {
            const size_t o = ((size_t)(b * SEG + seg) * N_ + n) * ED_ + d;
            hend[o]  = h[n];
            pprod[o] = P[n];
        }
    }
}

// Phase 2: parallel over (b,n,d) = 32768 threads, serial over SEG segments.
__global__ __launch_bounds__(256)
void ssm_combine_k(const float* __restrict__ hend, const float* __restrict__ pprod,
                   float* __restrict__ hinit)
{
    const int gid = blockIdx.x * 256 + threadIdx.x;   // 0..32767
    const int d = gid & (ED_ - 1);
    const int n = (gid >> 10) & (N_ - 1);
    const int b = gid >> 14;
    size_t o = ((size_t)(b * SEG) * N_ + n) * ED_ + d;
    const size_t stride = (size_t)N_ * ED_;
    float h = 0.0f;
    #pragma unroll 4
    for (int s = 0; s < SEG; ++s) {
        hinit[o] = h;
        h = fmaf(pprod[o], h, hend[o]);
        o += stride;
    }
}

// ---------------------------------------------------------------------------
extern "C" void kernel_launch(void* const* d_in, const int* in_sizes, int n_in,
                              void* d_out, int out_size, void* d_ws, size_t ws_size,
                              hipStream_t stream)
{
    const float* x      = (const float*)d_in[0];
    const float* p_Wi   = (const float*)d_in[1];
    const float* p_bi   = (const float*)d_in[2];
    const float* p_bh   = (const float*)d_in[3];
    const float* p_Wo   = (const float*)d_in[4];
    const float* p_bo   = (const float*)d_in[5];
    const float* m_norm = (const float*)d_in[6];
    const float* m_inW  = (const float*)d_in[7];
    const float* m_cw   = (const float*)d_in[8];
    const float* m_cb   = (const float*)d_in[9];
    const float* m_xpW  = (const float*)d_in[10];
    const float* m_dtW  = (const float*)d_in[11];
    const float* m_dtb  = (const float*)d_in[12];
    const float* m_Alog = (const float*)d_in[13];
    const float* m_D    = (const float*)d_in[14];
    const float* m_outW = (const float*)d_in[15];
    const float* d_Wi   = (const float*)d_in[16];
    const float* d_bi   = (const float*)d_in[17];
    const float* d_bh   = (const float*)d_in[18];
    const float* d_Wo   = (const float*)d_in[19];
    const float* d_bo   = (const float*)d_in[20];
    float* out_f = (float*)d_out;
    float* ws = (float*)d_ws;

    // ---- workspace layout (floats), total 25,149,440 = 100.6 MB ----
    float* OUT   = ws;                 // 2,097,152
    float* XCR   = ws + 2097152;       // 4,194,304 (conv input; later HEND/PPROD, CPART2)
    float* Z     = ws + 6291456;       // 4,194,304 (z half, live till scan3)
    float* XC    = ws + 10485760;      // 4,194,304 (post-conv f32)
    float* DBL   = ws + 14680064;      // 262,144
    float* DELTA = ws + 14942208;      // 4,194,304 (hosts xproj split-K partials first)
    float* HINIT = ws + 19136512;      // 2,097,152
    float* BF    = ws + 21233664;      // 2,097,152 (bf16 activations)
    float* WT    = ws + 23330816;      // 1,818,624 (bf16 transposed weights)

    // aliases
    float* HEND   = XCR;                // 2,097,152 (after conv consumed XCR)
    float* PPROD  = XCR + 2097152;      // 2,097,152
    float* CPARTX = DELTA;              // 8 x 262,144 (before dt-gemm writes DELTA)
    float* CPART2 = XCR;                // tail
    float* H2     = DBL;                // tail (262,144)
    __hip_bfloat16* Xb   = (__hip_bfloat16*)BF;              // 4096x128
    __hip_bfloat16* H1b  = (__hip_bfloat16*)(BF + 262144);   // 4096x512
    __hip_bfloat16* XNb  = (__hip_bfloat16*)BF;              // 4096x512
    __hip_bfloat16* XCb  = (__hip_bfloat16*)BF;              // 4096x1024
    __hip_bfloat16* YB   = (__hip_bfloat16*)BF;              // 4096x1024
    __hip_bfloat16* OUTb = (__hip_bfloat16*)XC;              // tail (4096x512)

    // transposed bf16 weights (offsets in bf16 units)
    __hip_bfloat16* WTu     = (__hip_bfloat16*)WT;
    __hip_bfloat16* T_pWi   = WTu;            // [512][128]
    __hip_bfloat16* T_pWo   = WTu + 65536;    // [512][512]
    __hip_bfloat16* T_inW0  = WTu + 327680;   // [2048][512]
    __hip_bfloat16* T_inW1  = WTu + 1376256;
    __hip_bfloat16* T_xpW0  = WTu + 2424832;  // [64][1024]
    __hip_bfloat16* T_xpW1  = WTu + 2490368;
    __hip_bfloat16* T_outW0 = WTu + 2555904;  // [512][1024]
    __hip_bfloat16* T_outW1 = WTu + 3080192;
    __hip_bfloat16* T_dWi   = WTu + 3604480;  // [64][512]

    const dim3 blk(256);

    // ---- weight conversions ----
    cvt_bf16_k<<<dim3(2048), blk, 0, stream>>>(x, Xb, M_TOK * IN_);
    transpose_bf16_k<<<dim3(4, 16), blk, 0, stream>>>(p_Wi, T_pWi, IN_, H_);
    transpose_bf16_k<<<dim3(16, 16), blk, 0, stream>>>(p_Wo, T_pWo, H_, H_);
    transpose_bf16_k<<<dim3(16, 64), blk, 0, stream>>>(m_inW, T_inW0, H_, 2 * ED_);
    transpose_bf16_k<<<dim3(16, 64), blk, 0, stream>>>(m_inW + (size_t)H_ * 2 * ED_, T_inW1, H_, 2 * ED_);
    transpose_bf16_k<<<dim3(32, 2), blk, 0, stream>>>(m_xpW, T_xpW0, ED_, 64);
    transpose_bf16_k<<<dim3(32, 2), blk, 0, stream>>>(m_xpW + (size_t)ED_ * 64, T_xpW1, ED_, 64);
    transpose_bf16_k<<<dim3(32, 16), blk, 0, stream>>>(m_outW, T_outW0, ED_, H_);
    transpose_bf16_k<<<dim3(32, 16), blk, 0, stream>>>(m_outW + (size_t)ED_ * H_, T_outW1, ED_, H_);
    transpose_bf16_k<<<dim3(16, 2), blk, 0, stream>>>(d_Wi, T_dWi, H_, OUT_);

    // ---- liquid1 ----
    mfma_gemm<128, 64, 2><<<dim3(32, 8), blk, 0, stream>>>(
        (const ushort*)Xb, IN_, (const ushort*)T_pWi, IN_, p_bi, p_bh,
        nullptr, H1b, H_, M_TOK, H_, IN_);
    mfma_gemm<128, 64, 3><<<dim3(32, 8), blk, 0, stream>>>(
        (const ushort*)H1b, H_, (const ushort*)T_pWo, H_, p_bo, nullptr,
        OUT, nullptr, H_, M_TOK, H_, H_);

    for (int l = 0; l < NL_; ++l) {
        const float* nw   = m_norm + l * H_;
        const float* cw   = m_cw   + l * ED_ * K_;
        const float* cb   = m_cb   + l * ED_;
        const float* dtW  = m_dtW  + l * DR_ * ED_;
        const float* dtb  = m_dtb  + l * ED_;
        const float* Alog = m_Alog + l * ED_ * N_;
        const float* Dv   = m_D    + l * ED_;
        const __hip_bfloat16* TinW  = l ? T_inW1  : T_inW0;
        const __hip_bfloat16* TxpW  = l ? T_xpW1  : T_xpW0;
        const __hip_bfloat16* ToutW = l ? T_outW1 : T_outW0;

        rmsnorm_k<<<dim3(M_TOK), blk, 0, stream>>>(OUT, nw, XNb);
        // in_W split: xc half and z half into separate de-interleaved buffers
        mfma_gemm<128, 128, 0><<<dim3(32, 8), blk, 0, stream>>>(
            (const ushort*)XNb, H_, (const ushort*)TinW, H_, nullptr, nullptr,
            XCR, nullptr, ED_, M_TOK, ED_, H_);
        mfma_gemm<128, 128, 0><<<dim3(32, 8), blk, 0, stream>>>(
            (const ushort*)XNb, H_, (const ushort*)(TinW + (size_t)ED_ * H_), H_,
            nullptr, nullptr, Z, nullptr, ED_, M_TOK, ED_, H_);
        conv_silu_k<<<dim3(M_TOK * ED_ / 256), blk, 0, stream>>>(XCR, cw, cb, XC, XCb);
        mfma_gemm<128, 64, 4><<<dim3(32, 1, 8), blk, 0, stream>>>(
            (const ushort*)XCb, ED_, (const ushort*)TxpW, ED_, nullptr, nullptr,
            CPARTX, nullptr, 64, M_TOK, 64, ED_ / 8);
        reduce_part_k<8, 0, false, false><<<dim3(1024), blk, 0, stream>>>(
            CPARTX, nullptr, nullptr, DBL, M_TOK * 64, 64);
        gemm_f32<2, true, false, false, false><<<dim3(64, 16), blk, 0, stream>>>(
            DBL, 64, dtW, ED_, dtb, nullptr, DELTA, ED_, M_TOK, ED_, DR_);
        ssm_scan_k<false><<<dim3(512), blk, 0, stream>>>(
            DELTA, XC, DBL, nullptr, Alog, nullptr, HEND, PPROD, nullptr, nullptr);
        ssm_combine_k<<<dim3(128), blk, 0, stream>>>(HEND, PPROD, HINIT);
        ssm_scan_k<true><<<dim3(512), blk, 0, stream>>>(
            DELTA, XC, DBL, Z, Alog, Dv, nullptr, nullptr, HINIT, YB);
        mfma_gemm<128, 64, 1><<<dim3(32, 8), blk, 0, stream>>>(
            (const ushort*)YB, ED_, (const ushort*)ToutW, ED_, nullptr, nullptr,
            OUT, nullptr, H_, M_TOK, H_, ED_);
    }

    // ---- liquid2 + final ----
    cvt_bf16_k<<<dim3(8192), blk, 0, stream>>>(OUT, OUTb, M_TOK * H_);
    mfma_gemm<128, 64, 4><<<dim3(32, 1, 8), blk, 0, stream>>>(
        (const ushort*)OUTb, H_, (const ushort*)T_dWi, H_, nullptr, nullptr,
        CPART2, nullptr, 64, M_TOK, 64, H_ / 8);
    reduce_part_k<8, 1, true, true><<<dim3(1024), blk, 0, stream>>>(
        CPART2, d_bi, d_bh, H2, M_TOK * 64, 64);
    gemm_f32<0, true, false, false, true><<<dim3(64, 1), blk, 0, stream>>>(
        H2, 64, d_Wo, 64, d_bo, nullptr, out_f, 64, M_TOK, 64, 64);
}

// Round 4
// 358.406 us; speedup vs baseline: 2.6392x; 1.2702x over previous
//
#include <hip/hip_runtime.h>
#include <hip/hip_bf16.h>
#include <cstdint>
#include <cstddef>

// Problem constants
#define B_   2
#define L_   2048
#define IN_  128
#define H_   512
#define OUT_ 64
#define NL_  2
#define ED_  1024
#define N_   16
#define DR_  32
#define K_   4

static constexpr int M_TOK = B_ * L_;   // 4096 tokens
static constexpr int SEG   = 64;        // scan segments
static constexpr int TS    = L_ / SEG;  // 32 steps per segment

typedef __attribute__((ext_vector_type(8))) short bhalf8;   // 8 bf16 (4 VGPRs)
typedef __attribute__((ext_vector_type(4))) float floatx4;  // MFMA accumulator

// direct global->LDS 16B/lane (dest = wave-uniform base + lane*16)
__device__ __forceinline__ void gld_lds16(const ushort* g, ushort* l)
{
    __builtin_amdgcn_global_load_lds(
        (const __attribute__((address_space(1))) unsigned int*)g,
        (__attribute__((address_space(3))) unsigned int*)l, 16, 0, 0);
}

// ---------------------------------------------------------------------------
// bf16 MFMA GEMM: C[M,N] = epi(A[M,K] @ B[K,N]), B supplied TRANSPOSED [N][K].
// 256 thr = 4 waves (2x2 of (BM/2)x(BN/2)), global_load_lds staging, linear LDS.
// EPI: 0 plain f32, 1 C+=v, 2 tanh(v+b1+b2)->bf16, 3 v+b1->f32,
//      4 split-K partial C[kz*M*N+row*N+col]=v, 5 w=v+b1; out=w-tanh(w),
//      6 softplus(v+b1)->f32
// DUAL: grid.z=2 selects (Bt,C) vs (Bt2,C2), same A.
// ---------------------------------------------------------------------------
template<int BM, int BN, int BK, int EPI, bool DUAL>
__global__ __launch_bounds__(256)
void mfma_gemm(const ushort* __restrict__ A, int lda,
               const ushort* Bt, int ldb,
               const ushort* Bt2, float* C2,
               const float* __restrict__ b1, const float* __restrict__ b2,
               float* C, __hip_bfloat16* Cb, int ldc,
               int M, int N, int kc)
{
    __shared__ __align__(16) ushort As[BM * BK];
    __shared__ __align__(16) ushort Bs[BN * BK];

    const int tid  = threadIdx.x;
    const int bm   = blockIdx.x * BM, bn = blockIdx.y * BN;
    int kz = 0, kbeg = 0;
    if (DUAL) {
        if (blockIdx.z) { Bt = Bt2; C = C2; }
    } else {
        kz = blockIdx.z; kbeg = kz * kc;
    }
    const int lane = tid & 63, wave = tid >> 6;
    const int wr = wave >> 1, wc = wave & 1;
    constexpr int WM = BM / 2, WN = BN / 2;
    constexpr int FM = WM / 16, FN = WN / 16;
    const int fr = lane & 15, fg = lane >> 4;

    // staging geometry: 1KB chunks (64 lanes x 16B)
    constexpr int ACH = BM * BK / 512;   // A chunks
    constexpr int BCH = BN * BK / 512;   // B chunks
    constexpr int RPC = 512 / BK;        // rows per chunk
    constexpr int LPR = BK / 8;          // lanes per row
    const int sr = lane / LPR;
    const int sc = (lane % LPR) * 8;

    floatx4 acc[FM][FN] = {};

    for (int k0 = kbeg; k0 < kbeg + kc; k0 += BK) {
        #pragma unroll
        for (int i = 0; i < ACH / 4; ++i) {
            const int ci = wave * (ACH / 4) + i;
            const int r  = ci * RPC + sr;
            gld_lds16(&A[(size_t)(bm + r) * lda + k0 + sc], &As[ci * 512]);
        }
        #pragma unroll
        for (int i = 0; i < BCH / 4; ++i) {
            const int ci = wave * (BCH / 4) + i;
            const int r  = ci * RPC + sr;
            gld_lds16(&Bt[(size_t)(bn + r) * ldb + k0 + sc], &Bs[ci * 512]);
        }
        __syncthreads();
        #pragma unroll
        for (int kk = 0; kk < BK; kk += 32) {
            bhalf8 fa[FM], fb[FN];
            #pragma unroll
            for (int m = 0; m < FM; ++m)
                fa[m] = *reinterpret_cast<const bhalf8*>(
                    &As[(wr * WM + m * 16 + fr) * BK + kk + fg * 8]);
            #pragma unroll
            for (int n = 0; n < FN; ++n)
                fb[n] = *reinterpret_cast<const bhalf8*>(
                    &Bs[(wc * WN + n * 16 + fr) * BK + kk + fg * 8]);
            #pragma unroll
            for (int m = 0; m < FM; ++m)
                #pragma unroll
                for (int n = 0; n < FN; ++n)
                    acc[m][n] = __builtin_amdgcn_mfma_f32_16x16x32_bf16(
                        fa[m], fb[n], acc[m][n], 0, 0, 0);
        }
        __syncthreads();
    }

    #pragma unroll
    for (int m = 0; m < FM; ++m) {
        #pragma unroll
        for (int n = 0; n < FN; ++n) {
            const int row0 = bm + wr * WM + m * 16 + fg * 4;
            const int col  = bn + wc * WN + n * 16 + fr;
            #pragma unroll
            for (int r = 0; r < 4; ++r) {
                float v = acc[m][n][r];
                const int row = row0 + r;
                if (EPI == 0) {
                    C[(size_t)row * ldc + col] = v;
                } else if (EPI == 1) {
                    C[(size_t)row * ldc + col] += v;
                } else if (EPI == 2) {
                    Cb[(size_t)row * ldc + col] =
                        __float2bfloat16(tanhf(v + b1[col] + b2[col]));
                } else if (EPI == 3) {
                    C[(size_t)row * ldc + col] = v + b1[col];
                } else if (EPI == 4) {
                    C[(size_t)kz * M * N + (size_t)row * N + col] = v;
                } else if (EPI == 5) {
                    const float w = v + b1[col];
                    C[(size_t)row * ldc + col] = w - tanhf(w);
                } else if (EPI == 6) {
                    const float w = v + b1[col];
                    C[(size_t)row * ldc + col] =
                        fmaxf(w, 0.0f) + log1pf(expf(-fabsf(w)));
                }
            }
        }
    }
}

// split-K reduce; OUTMODE: 0=f32, 1=bf16, 2=both
template<int NP, int ACT, bool B1, bool B2, int OUTMODE>
__global__ __launch_bounds__(256)
void reduce_part_k(const float* __restrict__ P, const float* __restrict__ b1,
                   const float* __restrict__ b2, float* __restrict__ Of,
                   __hip_bfloat16* __restrict__ Ob, int MN, int Ncols)
{
    const int i = blockIdx.x * 256 + threadIdx.x;
    float s = 0.0f;
    #pragma unroll
    for (int z = 0; z < NP; ++z) s += P[(size_t)z * MN + i];
    const int col = i & (Ncols - 1);
    if (B1) s += b1[col];
    if (B2) s += b2[col];
    if (ACT == 1) s = tanhf(s);
    if (OUTMODE == 0 || OUTMODE == 2) Of[i] = s;
    if (OUTMODE == 1 || OUTMODE == 2) Ob[i] = __float2bfloat16(s);
}

// f32 [K][N] -> bf16 [N][K] transpose-convert (32x32 LDS tile)
__global__ __launch_bounds__(256)
void transpose_bf16_k(const float* __restrict__ W, __hip_bfloat16* __restrict__ Wt,
                      int K, int N)
{
    __shared__ float t[32][33];
    const int k0 = blockIdx.x * 32, n0 = blockIdx.y * 32;
    const int c = threadIdx.x & 31, r4 = threadIdx.x >> 5;
    #pragma unroll
    for (int i = 0; i < 4; ++i) {
        int r = r4 + i * 8;
        t[r][c] = W[(size_t)(k0 + r) * N + n0 + c];
    }
    __syncthreads();
    #pragma unroll
    for (int i = 0; i < 4; ++i) {
        int r = r4 + i * 8;
        Wt[(size_t)(n0 + r) * K + k0 + c] = __float2bfloat16(t[c][r]);
    }
}

__global__ __launch_bounds__(256)
void cvt_bf16_k(const float* __restrict__ in, __hip_bfloat16* __restrict__ out, int n)
{
    const int i = blockIdx.x * 256 + threadIdx.x;
    if (i < n) out[i] = __float2bfloat16(in[i]);
}

// ---------------------------------------------------------------------------
// RMSNorm over H=512 -> bf16 out
// ---------------------------------------------------------------------------
__global__ __launch_bounds__(256)
void rmsnorm_k(const float* __restrict__ x, const float* __restrict__ w,
               __hip_bfloat16* __restrict__ o)
{
    const int row = blockIdx.x;
    const int tid = threadIdx.x;
    const float* xr = x + (size_t)row * H_;
    float v0 = xr[tid], v1 = xr[tid + 256];
    float s = v0 * v0 + v1 * v1;
    #pragma unroll
    for (int off = 32; off > 0; off >>= 1) s += __shfl_down(s, off, 64);
    __shared__ float ps[4];
    __shared__ float scale_s;
    const int wave = tid >> 6, lane = tid & 63;
    if (lane == 0) ps[wave] = s;
    __syncthreads();
    if (tid == 0) {
        float tot = ps[0] + ps[1] + ps[2] + ps[3];
        scale_s = rsqrtf(tot * (1.0f / H_) + 1e-5f);
    }
    __syncthreads();
    const float sc = scale_s;
    o[(size_t)row * H_ + tid]       = __float2bfloat16(v0 * sc * w[tid]);
    o[(size_t)row * H_ + tid + 256] = __float2bfloat16(v1 * sc * w[tid + 256]);
}

// ---------------------------------------------------------------------------
// Depthwise causal conv (K=4) + SiLU; reads de-interleaved XCR (M_TOK x ED)
// ---------------------------------------------------------------------------
__global__ __launch_bounds__(256)
void conv_silu_k(const float* __restrict__ xcr, const float* __restrict__ cw,
                 const float* __restrict__ cb, float* __restrict__ xc,
                 __hip_bfloat16* __restrict__ xcb)
{
    const int idx = blockIdx.x * 256 + threadIdx.x;
    const int d = idx & (ED_ - 1);
    const int t = (idx >> 10) & (L_ - 1);
    const int b = idx >> 21;
    const size_t base = (size_t)(b * L_ + t) * ED_ + d;
    float4 w = *reinterpret_cast<const float4*>(&cw[d * 4]);
    float acc = cb[d];
    acc += w.w * xcr[base];
    if (t >= 1) acc += w.z * xcr[base - 1 * ED_];
    if (t >= 2) acc += w.y * xcr[base - 2 * ED_];
    if (t >= 3) acc += w.x * xcr[base - 3 * ED_];
    const float s = acc / (1.0f + __expf(-acc));
    xc[base] = s;
    xcb[base] = __float2bfloat16(s);
}

// ---------------------------------------------------------------------------
// SSM chunked scan; SEG=64, TS=32, grid 512 blocks. Register-prefetched:
// all TS delta/xc loads hoisted before the recurrence chain (fully unrolled).
// ---------------------------------------------------------------------------
template<bool P3>
__global__ __launch_bounds__(256)
void ssm_scan_k(const float* __restrict__ delta,
                const float* __restrict__ xc,
                const float* __restrict__ dbl,
                const float* __restrict__ zbuf,
                const float* __restrict__ A_log,
                const float* __restrict__ Dv,
                float* __restrict__ hend, float* __restrict__ pprod,
                const float* __restrict__ hinit,
                __hip_bfloat16* __restrict__ ybuf)
{
    __shared__ float bc[TS][32];
    const int bx   = blockIdx.x;
    const int seg  = bx & (SEG - 1);
    const int dblk = (bx >> 6) & 3;
    const int b    = bx >> 8;
    const int tid  = threadIdx.x;
    const int d    = dblk * 256 + tid;
    const size_t row0 = (size_t)(b * L_ + seg * TS);

    #pragma unroll
    for (int e = 0; e < (TS * 32) / 256; ++e) {
        int lin = tid + e * 256;
        bc[lin >> 5][lin & 31] = dbl[(row0 + (lin >> 5)) * 64 + 32 + (lin & 31)];
    }
    __syncthreads();

    float Av[N_];
    #pragma unroll
    for (int n = 0; n < N_; ++n) Av[n] = -expf(A_log[d * N_ + n]);

    // hoisted loads: issue all TS loads before the dependent chain
    float dv[TS], xv[TS];
    #pragma unroll
    for (int tt = 0; tt < TS; ++tt) dv[tt] = delta[(row0 + tt) * ED_ + d];
    #pragma unroll
    for (int tt = 0; tt < TS; ++tt) xv[tt] = xc[(row0 + tt) * ED_ + d];

    float h[N_], P[N_];
    if (P3) {
        #pragma unroll
        for (int n = 0; n < N_; ++n)
            h[n] = hinit[((size_t)(b * SEG + seg) * N_ + n) * ED_ + d];
    } else {
        #pragma unroll
        for (int n = 0; n < N_; ++n) { h[n] = 0.0f; P[n] = 1.0f; }
    }
    const float Dd = P3 ? Dv[d] : 0.0f;

    #pragma unroll
    for (int tt = 0; tt < TS; ++tt) {
        const float dvt = dv[tt];
        const float dx  = dvt * xv[tt];
        float ysum = 0.0f;
        #pragma unroll
        for (int n = 0; n < N_; ++n) {
            const float dA = __expf(dvt * Av[n]);
            h[n] = fmaf(dA, h[n], dx * bc[tt][n]);
            if (!P3) P[n] *= dA;
            else     ysum = fmaf(h[n], bc[tt][16 + n], ysum);
        }
        if (P3) {
            const float zv = zbuf[(row0 + tt) * ED_ + d];
            const float sz = zv / (1.0f + __expf(-zv));
            ybuf[(row0 + tt) * ED_ + d] =
                __float2bfloat16((ysum + Dd * xv[tt]) * sz);
        }
    }

    if (!P3) {
        #pragma unroll
        for (int n = 0; n < N_; ++n) {
            const size_t o = ((size_t)(b * SEG + seg) * N_ + n) * ED_ + d;
            hend[o]  = h[n];
            pprod[o] = P[n];
        }
    }
}

// Phase 2: parallel over (b,n,d) = 32768 threads, serial over SEG segments.
__global__ __launch_bounds__(256)
void ssm_combine_k(const float* __restrict__ hend, const float* __restrict__ pprod,
                   float* __restrict__ hinit)
{
    const int gid = blockIdx.x * 256 + threadIdx.x;   // 0..32767
    const int d = gid & (ED_ - 1);
    const int n = (gid >> 10) & (N_ - 1);
    const int b = gid >> 14;
    size_t o = ((size_t)(b * SEG) * N_ + n) * ED_ + d;
    const size_t stride = (size_t)N_ * ED_;
    float h = 0.0f;
    #pragma unroll 8
    for (int s = 0; s < SEG; ++s) {
        hinit[o] = h;
        h = fmaf(pprod[o], h, hend[o]);
        o += stride;
    }
}

// ---------------------------------------------------------------------------
extern "C" void kernel_launch(void* const* d_in, const int* in_sizes, int n_in,
                              void* d_out, int out_size, void* d_ws, size_t ws_size,
                              hipStream_t stream)
{
    const float* x      = (const float*)d_in[0];
    const float* p_Wi   = (const float*)d_in[1];
    const float* p_bi   = (const float*)d_in[2];
    const float* p_bh   = (const float*)d_in[3];
    const float* p_Wo   = (const float*)d_in[4];
    const float* p_bo   = (const float*)d_in[5];
    const float* m_norm = (const float*)d_in[6];
    const float* m_inW  = (const float*)d_in[7];
    const float* m_cw   = (const float*)d_in[8];
    const float* m_cb   = (const float*)d_in[9];
    const float* m_xpW  = (const float*)d_in[10];
    const float* m_dtW  = (const float*)d_in[11];
    const float* m_dtb  = (const float*)d_in[12];
    const float* m_Alog = (const float*)d_in[13];
    const float* m_D    = (const float*)d_in[14];
    const float* m_outW = (const float*)d_in[15];
    const float* d_Wi   = (const float*)d_in[16];
    const float* d_bi   = (const float*)d_in[17];
    const float* d_bh   = (const float*)d_in[18];
    const float* d_Wo   = (const float*)d_in[19];
    const float* d_bo   = (const float*)d_in[20];
    float* out_f = (float*)d_out;
    float* ws = (float*)d_ws;

    // ---- workspace layout (floats), total 25,315,328 = 101.3 MB ----
    float* OUT   = ws;                 // 2,097,152
    float* XCR   = ws + 2097152;       // 4,194,304 (conv in; later HEND/PPROD/CPART2)
    float* Z     = ws + 6291456;       // 4,194,304
    float* XC    = ws + 10485760;      // 4,194,304 (post-conv f32; later OUTb)
    float* DBL   = ws + 14680064;      // 262,144
    float* DELTA = ws + 14942208;      // 4,194,304 (hosts xproj split-K partials)
    float* HINIT = ws + 19136512;      // 2,097,152
    float* BF    = ws + 21233664;      // 2,097,152 (bf16 activations)
    float* WT    = ws + 23330816;      // 1,853,440 (bf16 transposed weights)
    float* DBLF  = ws + 25184256;      // 131,072  (bf16 dbl copy)

    // aliases
    float* HEND   = XCR;
    float* PPROD  = XCR + 2097152;
    float* CPARTX = DELTA;
    float* CPART2 = XCR;
    __hip_bfloat16* Xb   = (__hip_bfloat16*)BF;              // 4096x128
    __hip_bfloat16* H1b  = (__hip_bfloat16*)(BF + 262144);   // 4096x512
    __hip_bfloat16* XNb  = (__hip_bfloat16*)BF;              // 4096x512
    __hip_bfloat16* XCb  = (__hip_bfloat16*)BF;              // 4096x1024
    __hip_bfloat16* YB   = (__hip_bfloat16*)BF;              // 4096x1024
    __hip_bfloat16* H2b  = (__hip_bfloat16*)BF;              // 4096x64
    __hip_bfloat16* OUTb = (__hip_bfloat16*)XC;              // 4096x512
    __hip_bfloat16* DBLb = (__hip_bfloat16*)DBLF;            // 4096x64

    // transposed bf16 weights (offsets in bf16 units)
    __hip_bfloat16* WTu     = (__hip_bfloat16*)WT;
    __hip_bfloat16* T_pWi   = WTu;            // [512][128]
    __hip_bfloat16* T_pWo   = WTu + 65536;    // [512][512]
    __hip_bfloat16* T_inW0  = WTu + 327680;   // [2048][512]
    __hip_bfloat16* T_inW1  = WTu + 1376256;
    __hip_bfloat16* T_xpW0  = WTu + 2424832;  // [64][1024]
    __hip_bfloat16* T_xpW1  = WTu + 2490368;
    __hip_bfloat16* T_outW0 = WTu + 2555904;  // [512][1024]
    __hip_bfloat16* T_outW1 = WTu + 3080192;
    __hip_bfloat16* T_dWi   = WTu + 3604480;  // [64][512]
    __hip_bfloat16* T_dtW0  = WTu + 3637248;  // [1024][32]
    __hip_bfloat16* T_dtW1  = WTu + 3670016;
    __hip_bfloat16* T_dWo   = WTu + 3702784;  // [64][64]

    const dim3 blk(256);

    // ---- weight conversions ----
    cvt_bf16_k<<<dim3(2048), blk, 0, stream>>>(x, Xb, M_TOK * IN_);
    transpose_bf16_k<<<dim3(4, 16), blk, 0, stream>>>(p_Wi, T_pWi, IN_, H_);
    transpose_bf16_k<<<dim3(16, 16), blk, 0, stream>>>(p_Wo, T_pWo, H_, H_);
    transpose_bf16_k<<<dim3(16, 64), blk, 0, stream>>>(m_inW, T_inW0, H_, 2 * ED_);
    transpose_bf16_k<<<dim3(16, 64), blk, 0, stream>>>(m_inW + (size_t)H_ * 2 * ED_, T_inW1, H_, 2 * ED_);
    transpose_bf16_k<<<dim3(32, 2), blk, 0, stream>>>(m_xpW, T_xpW0, ED_, 64);
    transpose_bf16_k<<<dim3(32, 2), blk, 0, stream>>>(m_xpW + (size_t)ED_ * 64, T_xpW1, ED_, 64);
    transpose_bf16_k<<<dim3(32, 16), blk, 0, stream>>>(m_outW, T_outW0, ED_, H_);
    transpose_bf16_k<<<dim3(32, 16), blk, 0, stream>>>(m_outW + (size_t)ED_ * H_, T_outW1, ED_, H_);
    transpose_bf16_k<<<dim3(16, 2), blk, 0, stream>>>(d_Wi, T_dWi, H_, OUT_);
    transpose_bf16_k<<<dim3(1, 32), blk, 0, stream>>>(m_dtW, T_dtW0, DR_, ED_);
    transpose_bf16_k<<<dim3(1, 32), blk, 0, stream>>>(m_dtW + DR_ * ED_, T_dtW1, DR_, ED_);
    transpose_bf16_k<<<dim3(2, 2), blk, 0, stream>>>(d_Wo, T_dWo, OUT_, OUT_);

    // ---- liquid1 ----
    mfma_gemm<128, 64, 64, 2, false><<<dim3(32, 8), blk, 0, stream>>>(
        (const ushort*)Xb, IN_, (const ushort*)T_pWi, IN_, nullptr, nullptr,
        p_bi, p_bh, nullptr, H1b, H_, M_TOK, H_, IN_);
    mfma_gemm<128, 64, 64, 3, false><<<dim3(32, 8), blk, 0, stream>>>(
        (const ushort*)H1b, H_, (const ushort*)T_pWo, H_, nullptr, nullptr,
        p_bo, nullptr, OUT, nullptr, H_, M_TOK, H_, H_);

    for (int l = 0; l < NL_; ++l) {
        const float* nw   = m_norm + l * H_;
        const float* cw   = m_cw   + l * ED_ * K_;
        const float* cb   = m_cb   + l * ED_;
        const float* dtb  = m_dtb  + l * ED_;
        const float* Alog = m_Alog + l * ED_ * N_;
        const float* Dv   = m_D    + l * ED_;
        const __hip_bfloat16* TinW  = l ? T_inW1  : T_inW0;
        const __hip_bfloat16* TxpW  = l ? T_xpW1  : T_xpW0;
        const __hip_bfloat16* ToutW = l ? T_outW1 : T_outW0;
        const __hip_bfloat16* TdtW  = l ? T_dtW1  : T_dtW0;

        rmsnorm_k<<<dim3(M_TOK), blk, 0, stream>>>(OUT, nw, XNb);
        // in_W: both halves in one dual launch (de-interleaved outputs)
        mfma_gemm<128, 128, 64, 0, true><<<dim3(32, 8, 2), blk, 0, stream>>>(
            (const ushort*)XNb, H_, (const ushort*)TinW, H_,
            (const ushort*)(TinW + (size_t)ED_ * H_), Z,
            nullptr, nullptr, XCR, nullptr, ED_, M_TOK, ED_, H_);
        conv_silu_k<<<dim3(M_TOK * ED_ / 256), blk, 0, stream>>>(XCR, cw, cb, XC, XCb);
        mfma_gemm<128, 64, 64, 4, false><<<dim3(32, 1, 8), blk, 0, stream>>>(
            (const ushort*)XCb, ED_, (const ushort*)TxpW, ED_, nullptr, nullptr,
            nullptr, nullptr, CPARTX, nullptr, 64, M_TOK, 64, ED_ / 8);
        reduce_part_k<8, 0, false, false, 2><<<dim3(1024), blk, 0, stream>>>(
            CPARTX, nullptr, nullptr, DBL, DBLb, M_TOK * 64, 64);
        mfma_gemm<128, 64, 32, 6, false><<<dim3(32, 16), blk, 0, stream>>>(
            (const ushort*)DBLb, 64, (const ushort*)TdtW, DR_, nullptr, nullptr,
            dtb, nullptr, DELTA, nullptr, ED_, M_TOK, ED_, DR_);
        ssm_scan_k<false><<<dim3(512), blk, 0, stream>>>(
            DELTA, XC, DBL, nullptr, Alog, nullptr, HEND, PPROD, nullptr, nullptr);
        ssm_combine_k<<<dim3(128), blk, 0, stream>>>(HEND, PPROD, HINIT);
        ssm_scan_k<true><<<dim3(512), blk, 0, stream>>>(
            DELTA, XC, DBL, Z, Alog, Dv, nullptr, nullptr, HINIT, YB);
        mfma_gemm<128, 64, 64, 1, false><<<dim3(32, 8), blk, 0, stream>>>(
            (const ushort*)YB, ED_, (const ushort*)ToutW, ED_, nullptr, nullptr,
            nullptr, nullptr, OUT, nullptr, H_, M_TOK, H_, ED_);
    }

    // ---- liquid2 + final (fused v - tanh(v)) ----
    cvt_bf16_k<<<dim3(8192), blk, 0, stream>>>(OUT, OUTb, M_TOK * H_);
    mfma_gemm<128, 64, 64, 4, false><<<dim3(32, 1, 8), blk, 0, stream>>>(
        (const ushort*)OUTb, H_, (const ushort*)T_dWi, H_, nullptr, nullptr,
        nullptr, nullptr, CPART2, nullptr, 64, M_TOK, 64, H_ / 8);
    reduce_part_k<8, 1, true, true, 1><<<dim3(1024), blk, 0, stream>>>(
        CPART2, d_bi, d_bh, nullptr, H2b, M_TOK * 64, 64);
    mfma_gemm<128, 64, 64, 5, false><<<dim3(32, 1), blk, 0, stream>>>(
        (const ushort*)H2b, OUT_, (const ushort*)T_dWo, OUT_, nullptr, nullptr,
        d_bo, nullptr, out_f, nullptr, OUT_, M_TOK, OUT_, OUT_);
}

// Round 5
// 342.503 us; speedup vs baseline: 2.7618x; 1.0464x over previous
//
#include <hip/hip_runtime.h>
#include <hip/hip_bf16.h>
#include <cstdint>
#include <cstddef>

// Problem constants
#define B_   2
#define L_   2048
#define IN_  128
#define H_   512
#define OUT_ 64
#define NL_  2
#define ED_  1024
#define N_   16
#define DR_  32
#define K_   4

static constexpr int M_TOK = B_ * L_;   // 4096 tokens
static constexpr int SEG   = 64;        // scan segments
static constexpr int TS    = L_ / SEG;  // 32 steps per segment

typedef __attribute__((ext_vector_type(8))) short bhalf8;   // 8 bf16 (4 VGPRs)
typedef __attribute__((ext_vector_type(4))) float floatx4;  // MFMA accumulator

__device__ __forceinline__ ushort bf16bits(float f)
{
    __hip_bfloat16 h = __float2bfloat16(f);
    return *reinterpret_cast<ushort*>(&h);
}

// direct global->LDS 16B/lane (dest = wave-uniform base + lane*16)
__device__ __forceinline__ void gld_lds16(const ushort* g, ushort* l)
{
    __builtin_amdgcn_global_load_lds(
        (const __attribute__((address_space(1))) unsigned int*)g,
        (__attribute__((address_space(3))) unsigned int*)l, 16, 0, 0);
}

// ---------------------------------------------------------------------------
// bf16 MFMA GEMM: C[M,N] = epi(A[M,K] @ B[K,N]), B supplied TRANSPOSED [N][K].
// 256 thr = 4 waves (2x2 of (BM/2)x(BN/2)), global_load_lds staging, linear LDS.
// EPI: 0 plain f32, 1 C+=v, 2 tanh(v+b1+b2)->bf16, 3 v+b1->f32,
//      4 split-K partial C[kz*M*N+row*N+col]=v, 5 w=v+b1; out=w-tanh(w),
//      6 softplus(v+b1)->f32, 7 w=C+v; C=w and Cb=bf16(w)
// DUAL: grid.z=2 selects (Bt,C) vs (Bt2,C2), same A.
// ---------------------------------------------------------------------------
template<int BM, int BN, int BK, int EPI, bool DUAL>
__global__ __launch_bounds__(256)
void mfma_gemm(const ushort* __restrict__ A, int lda,
               const ushort* Bt, int ldb,
               const ushort* Bt2, float* C2,
               const float* __restrict__ b1, const float* __restrict__ b2,
               float* C, __hip_bfloat16* Cb, int ldc,
               int M, int N, int kc)
{
    __shared__ __align__(16) ushort As[BM * BK];
    __shared__ __align__(16) ushort Bs[BN * BK];

    const int tid  = threadIdx.x;
    const int bm   = blockIdx.x * BM, bn = blockIdx.y * BN;
    int kz = 0, kbeg = 0;
    if (DUAL) {
        if (blockIdx.z) { Bt = Bt2; C = C2; }
    } else {
        kz = blockIdx.z; kbeg = kz * kc;
    }
    const int lane = tid & 63, wave = tid >> 6;
    const int wr = wave >> 1, wc = wave & 1;
    constexpr int WM = BM / 2, WN = BN / 2;
    constexpr int FM = WM / 16, FN = WN / 16;
    const int fr = lane & 15, fg = lane >> 4;

    // staging geometry: 1KB chunks (64 lanes x 16B)
    constexpr int ACH = BM * BK / 512;   // A chunks
    constexpr int BCH = BN * BK / 512;   // B chunks
    constexpr int RPC = 512 / BK;        // rows per chunk
    constexpr int LPR = BK / 8;          // lanes per row
    const int sr = lane / LPR;
    const int sc = (lane % LPR) * 8;

    floatx4 acc[FM][FN] = {};

    for (int k0 = kbeg; k0 < kbeg + kc; k0 += BK) {
        #pragma unroll
        for (int i = 0; i < ACH / 4; ++i) {
            const int ci = wave * (ACH / 4) + i;
            const int r  = ci * RPC + sr;
            gld_lds16(&A[(size_t)(bm + r) * lda + k0 + sc], &As[ci * 512]);
        }
        #pragma unroll
        for (int i = 0; i < BCH / 4; ++i) {
            const int ci = wave * (BCH / 4) + i;
            const int r  = ci * RPC + sr;
            gld_lds16(&Bt[(size_t)(bn + r) * ldb + k0 + sc], &Bs[ci * 512]);
        }
        __syncthreads();
        #pragma unroll
        for (int kk = 0; kk < BK; kk += 32) {
            bhalf8 fa[FM], fb[FN];
            #pragma unroll
            for (int m = 0; m < FM; ++m)
                fa[m] = *reinterpret_cast<const bhalf8*>(
                    &As[(wr * WM + m * 16 + fr) * BK + kk + fg * 8]);
            #pragma unroll
            for (int n = 0; n < FN; ++n)
                fb[n] = *reinterpret_cast<const bhalf8*>(
                    &Bs[(wc * WN + n * 16 + fr) * BK + kk + fg * 8]);
            #pragma unroll
            for (int m = 0; m < FM; ++m)
                #pragma unroll
                for (int n = 0; n < FN; ++n)
                    acc[m][n] = __builtin_amdgcn_mfma_f32_16x16x32_bf16(
                        fa[m], fb[n], acc[m][n], 0, 0, 0);
        }
        __syncthreads();
    }

    #pragma unroll
    for (int m = 0; m < FM; ++m) {
        #pragma unroll
        for (int n = 0; n < FN; ++n) {
            const int row0 = bm + wr * WM + m * 16 + fg * 4;
            const int col  = bn + wc * WN + n * 16 + fr;
            #pragma unroll
            for (int r = 0; r < 4; ++r) {
                float v = acc[m][n][r];
                const int row = row0 + r;
                if (EPI == 0) {
                    C[(size_t)row * ldc + col] = v;
                } else if (EPI == 1) {
                    C[(size_t)row * ldc + col] += v;
                } else if (EPI == 2) {
                    Cb[(size_t)row * ldc + col] =
                        __float2bfloat16(tanhf(v + b1[col] + b2[col]));
                } else if (EPI == 3) {
                    C[(size_t)row * ldc + col] = v + b1[col];
                } else if (EPI == 4) {
                    C[(size_t)kz * M * N + (size_t)row * N + col] = v;
                } else if (EPI == 5) {
                    const float w = v + b1[col];
                    C[(size_t)row * ldc + col] = w - tanhf(w);
                } else if (EPI == 6) {
                    const float w = v + b1[col];
                    C[(size_t)row * ldc + col] =
                        fmaxf(w, 0.0f) + log1pf(expf(-fabsf(w)));
                } else if (EPI == 7) {
                    float* cp = C + (size_t)row * ldc + col;
                    const float w = *cp + v;
                    *cp = w;
                    Cb[(size_t)row * ldc + col] = __float2bfloat16(w);
                }
            }
        }
    }
}

// split-K reduce; OUTMODE: 0=f32, 1=bf16, 2=both
template<int NP, int ACT, bool B1, bool B2, int OUTMODE>
__global__ __launch_bounds__(256)
void reduce_part_k(const float* __restrict__ P, const float* __restrict__ b1,
                   const float* __restrict__ b2, float* __restrict__ Of,
                   __hip_bfloat16* __restrict__ Ob, int MN, int Ncols)
{
    const int i = blockIdx.x * 256 + threadIdx.x;
    float s = 0.0f;
    #pragma unroll
    for (int z = 0; z < NP; ++z) s += P[(size_t)z * MN + i];
    const int col = i & (Ncols - 1);
    if (B1) s += b1[col];
    if (B2) s += b2[col];
    if (ACT == 1) s = tanhf(s);
    if (OUTMODE == 0 || OUTMODE == 2) Of[i] = s;
    if (OUTMODE == 1 || OUTMODE == 2) Ob[i] = __float2bfloat16(s);
}

// ---------------------------------------------------------------------------
// prep mega-kernel: x->bf16 cvt + all 12 weight transpose-converts, one launch.
// ---------------------------------------------------------------------------
__device__ __forceinline__ void tr32(float (*t)[33],
                                     const float* __restrict__ W,
                                     __hip_bfloat16* __restrict__ Wt,
                                     int K, int N, int local, int gx, int tid)
{
    const int kx = local % gx, ny = local / gx;
    const int k0 = kx * 32, n0 = ny * 32;
    const int c = tid & 31, r4 = tid >> 5;
    #pragma unroll
    for (int i = 0; i < 4; ++i) {
        const int rr = r4 + i * 8;
        t[rr][c] = W[(size_t)(k0 + rr) * N + n0 + c];
    }
    __syncthreads();
    #pragma unroll
    for (int i = 0; i < 4; ++i) {
        const int rr = r4 + i * 8;
        Wt[(size_t)(n0 + rr) * K + k0 + c] = __float2bfloat16(t[c][rr]);
    }
}

__global__ __launch_bounds__(256)
void prep_k(const float* __restrict__ x, __hip_bfloat16* __restrict__ Xb,
            const float* pWi, __hip_bfloat16* TpWi,
            const float* pWo, __hip_bfloat16* TpWo,
            const float* inW, __hip_bfloat16* TinW0, __hip_bfloat16* TinW1,
            const float* xpW, __hip_bfloat16* TxpW0, __hip_bfloat16* TxpW1,
            const float* outW, __hip_bfloat16* ToutW0, __hip_bfloat16* ToutW1,
            const float* dWi, __hip_bfloat16* TdWi,
            const float* dtW, __hip_bfloat16* TdtW0, __hip_bfloat16* TdtW1,
            const float* dWo, __hip_bfloat16* TdWo)
{
    __shared__ float t[32][33];
    const int tid = threadIdx.x;
    int r = blockIdx.x;

    if (r < 512) {   // x -> bf16, float4 vectorized
        const int i = (r * 256 + tid) * 4;
        const float4 v = *reinterpret_cast<const float4*>(&x[i]);
        ushort4 u;
        u.x = bf16bits(v.x); u.y = bf16bits(v.y);
        u.z = bf16bits(v.z); u.w = bf16bits(v.w);
        *reinterpret_cast<ushort4*>(&Xb[i]) = u;
        return;
    }
    r -= 512;
    if (r < 64)   { tr32(t, pWi, TpWi, IN_, H_, r, 4, tid); return; }   r -= 64;
    if (r < 256)  { tr32(t, pWo, TpWo, H_, H_, r, 16, tid); return; }   r -= 256;
    if (r < 1024) { tr32(t, inW, TinW0, H_, 2 * ED_, r, 16, tid); return; } r -= 1024;
    if (r < 1024) { tr32(t, inW + (size_t)H_ * 2 * ED_, TinW1, H_, 2 * ED_, r, 16, tid); return; } r -= 1024;
    if (r < 64)   { tr32(t, xpW, TxpW0, ED_, 64, r, 32, tid); return; } r -= 64;
    if (r < 64)   { tr32(t, xpW + (size_t)ED_ * 64, TxpW1, ED_, 64, r, 32, tid); return; } r -= 64;
    if (r < 512)  { tr32(t, outW, ToutW0, ED_, H_, r, 32, tid); return; } r -= 512;
    if (r < 512)  { tr32(t, outW + (size_t)ED_ * H_, ToutW1, ED_, H_, r, 32, tid); return; } r -= 512;
    if (r < 32)   { tr32(t, dWi, TdWi, H_, OUT_, r, 16, tid); return; } r -= 32;
    if (r < 32)   { tr32(t, dtW, TdtW0, DR_, ED_, r, 1, tid); return; } r -= 32;
    if (r < 32)   { tr32(t, dtW + DR_ * ED_, TdtW1, DR_, ED_, r, 1, tid); return; } r -= 32;
    tr32(t, dWo, TdWo, OUT_, OUT_, r, 2, tid);
}
static constexpr int PREP_BLOCKS = 512 + 64 + 256 + 1024 + 1024 + 64 + 64 + 512 + 512 + 32 + 32 + 32 + 4;

// ---------------------------------------------------------------------------
// RMSNorm over H=512 -> bf16 out
// ---------------------------------------------------------------------------
__global__ __launch_bounds__(256)
void rmsnorm_k(const float* __restrict__ x, const float* __restrict__ w,
               __hip_bfloat16* __restrict__ o)
{
    const int row = blockIdx.x;
    const int tid = threadIdx.x;
    const float* xr = x + (size_t)row * H_;
    float v0 = xr[tid], v1 = xr[tid + 256];
    float s = v0 * v0 + v1 * v1;
    #pragma unroll
    for (int off = 32; off > 0; off >>= 1) s += __shfl_down(s, off, 64);
    __shared__ float ps[4];
    __shared__ float scale_s;
    const int wave = tid >> 6, lane = tid & 63;
    if (lane == 0) ps[wave] = s;
    __syncthreads();
    if (tid == 0) {
        float tot = ps[0] + ps[1] + ps[2] + ps[3];
        scale_s = rsqrtf(tot * (1.0f / H_) + 1e-5f);
    }
    __syncthreads();
    const float sc = scale_s;
    o[(size_t)row * H_ + tid]       = __float2bfloat16(v0 * sc * w[tid]);
    o[(size_t)row * H_ + tid + 256] = __float2bfloat16(v1 * sc * w[tid + 256]);
}

// ---------------------------------------------------------------------------
// Depthwise causal conv (K=4) + SiLU, float4 over d. Grid: M_TOK*ED/4/256.
// ---------------------------------------------------------------------------
__global__ __launch_bounds__(256)
void conv_silu_k(const float* __restrict__ xcr, const float* __restrict__ cw,
                 const float* __restrict__ cb, float* __restrict__ xc,
                 __hip_bfloat16* __restrict__ xcb)
{
    const int idx = blockIdx.x * 256 + threadIdx.x;   // over M_TOK*ED/4
    const int d4 = (idx & (ED_ / 4 - 1)) * 4;
    const int t  = (idx >> 8) & (L_ - 1);
    const int b  = idx >> 19;
    const size_t base = (size_t)(b * L_ + t) * ED_ + d4;

    float4 x0 = *reinterpret_cast<const float4*>(&xcr[base]);
    float4 x1 = {}, x2 = {}, x3 = {};
    if (t >= 1) x1 = *reinterpret_cast<const float4*>(&xcr[base - 1 * ED_]);
    if (t >= 2) x2 = *reinterpret_cast<const float4*>(&xcr[base - 2 * ED_]);
    if (t >= 3) x3 = *reinterpret_cast<const float4*>(&xcr[base - 3 * ED_]);
    const float4 bias = *reinterpret_cast<const float4*>(&cb[d4]);

    float4 out;
    ushort4 outb;
    #pragma unroll
    for (int j = 0; j < 4; ++j) {
        const float4 w = *reinterpret_cast<const float4*>(&cw[(d4 + j) * 4]);
        float acc = (&bias.x)[j];
        acc += w.w * (&x0.x)[j];
        acc += w.z * (&x1.x)[j];
        acc += w.y * (&x2.x)[j];
        acc += w.x * (&x3.x)[j];
        const float s = acc / (1.0f + __expf(-acc));
        (&out.x)[j] = s;
        (&outb.x)[j] = bf16bits(s);
    }
    *reinterpret_cast<float4*>(&xc[base]) = out;
    *reinterpret_cast<ushort4*>(&xcb[base]) = outb;
}

// ---------------------------------------------------------------------------
// SSM chunked scan, LDS-staged, 4-way n-split. SEG=64, TS=32.
// Block: 256 thr = 64 d-channels x 4 n-groups. Grid: B*SEG*(ED/64) = 2048.
// ---------------------------------------------------------------------------
template<bool P3>
__global__ __launch_bounds__(256)
void ssm_scan_k(const float* __restrict__ delta,
                const float* __restrict__ xc,
                const float* __restrict__ dbl,
                const float* __restrict__ zbuf,
                const float* __restrict__ A_log,
                const float* __restrict__ Dv,
                float* __restrict__ hend, float* __restrict__ pprod,
                const float* __restrict__ hinit,
                __hip_bfloat16* __restrict__ ybuf)
{
    __shared__ float sdl[TS][64];
    __shared__ float sxc[TS][64];
    __shared__ float bc[TS][32];   // [t][0:16]=B, [t][16:32]=C
    const int bx   = blockIdx.x;
    const int seg  = bx & (SEG - 1);
    const int dblk = (bx >> 6) & 15;
    const int b    = bx >> 10;
    const int tid  = threadIdx.x;
    const int dl   = tid >> 2;      // 0..63
    const int ng   = tid & 3;       // n-group: states ng*4..ng*4+3
    const int d    = dblk * 64 + dl;
    const int dbase = dblk * 64;
    const size_t row0 = (size_t)(b * L_ + seg * TS);

    #pragma unroll
    for (int e = 0; e < 8; ++e) {
        const int lin = tid + e * 256;
        sdl[lin >> 6][lin & 63] = delta[(row0 + (lin >> 6)) * ED_ + dbase + (lin & 63)];
    }
    #pragma unroll
    for (int e = 0; e < 8; ++e) {
        const int lin = tid + e * 256;
        sxc[lin >> 6][lin & 63] = xc[(row0 + (lin >> 6)) * ED_ + dbase + (lin & 63)];
    }
    #pragma unroll
    for (int e = 0; e < 4; ++e) {
        const int lin = tid + e * 256;
        bc[lin >> 5][lin & 31] = dbl[(row0 + (lin >> 5)) * 64 + 32 + (lin & 31)];
    }

    float Av[4];
    #pragma unroll
    for (int i = 0; i < 4; ++i) Av[i] = -expf(A_log[d * N_ + ng * 4 + i]);

    float h[4], P[4];
    if (P3) {
        #pragma unroll
        for (int i = 0; i < 4; ++i)
            h[i] = hinit[((size_t)(b * SEG + seg) * N_ + ng * 4 + i) * ED_ + d];
    } else {
        #pragma unroll
        for (int i = 0; i < 4; ++i) { h[i] = 0.0f; P[i] = 1.0f; }
    }
    const float Dd = P3 ? Dv[d] : 0.0f;
    __syncthreads();

    #pragma unroll
    for (int t = 0; t < TS; ++t) {
        const float dvt = sdl[t][dl];
        const float xvt = sxc[t][dl];
        const float dx  = dvt * xvt;
        float ysum = 0.0f;
        #pragma unroll
        for (int i = 0; i < 4; ++i) {
            const float dA = __expf(dvt * Av[i]);
            h[i] = fmaf(dA, h[i], dx * bc[t][ng * 4 + i]);
            if (!P3) P[i] *= dA;
            else     ysum = fmaf(h[i], bc[t][16 + ng * 4 + i], ysum);
        }
        if (P3) {
            float y2 = ysum + __shfl_xor(ysum, 1, 64);
            float y4 = y2 + __shfl_xor(y2, 2, 64);
            if (ng == 0) {
                const float zv = zbuf[(row0 + t) * ED_ + d];
                const float sz = zv / (1.0f + __expf(-zv));
                ybuf[(row0 + t) * ED_ + d] =
                    __float2bfloat16((y4 + Dd * xvt) * sz);
            }
        }
    }

    if (!P3) {
        #pragma unroll
        for (int i = 0; i < 4; ++i) {
            const size_t o = ((size_t)(b * SEG + seg) * N_ + ng * 4 + i) * ED_ + d;
            hend[o]  = h[i];
            pprod[o] = P[i];
        }
    }
}

// Phase 2: parallel over (b,n,d) = 32768 threads, serial over SEG segments.
__global__ __launch_bounds__(256)
void ssm_combine_k(const float* __restrict__ hend, const float* __restrict__ pprod,
                   float* __restrict__ hinit)
{
    const int gid = blockIdx.x * 256 + threadIdx.x;   // 0..32767
    const int d = gid & (ED_ - 1);
    const int n = (gid >> 10) & (N_ - 1);
    const int b = gid >> 14;
    size_t o = ((size_t)(b * SEG) * N_ + n) * ED_ + d;
    const size_t stride = (size_t)N_ * ED_;
    float h = 0.0f;
    #pragma unroll 8
    for (int s = 0; s < SEG; ++s) {
        hinit[o] = h;
        h = fmaf(pprod[o], h, hend[o]);
        o += stride;
    }
}

// ---------------------------------------------------------------------------
extern "C" void kernel_launch(void* const* d_in, const int* in_sizes, int n_in,
                              void* d_out, int out_size, void* d_ws, size_t ws_size,
                              hipStream_t stream)
{
    const float* x      = (const float*)d_in[0];
    const float* p_Wi   = (const float*)d_in[1];
    const float* p_bi   = (const float*)d_in[2];
    const float* p_bh   = (const float*)d_in[3];
    const float* p_Wo   = (const float*)d_in[4];
    const float* p_bo   = (const float*)d_in[5];
    const float* m_norm = (const float*)d_in[6];
    const float* m_inW  = (const float*)d_in[7];
    const float* m_cw   = (const float*)d_in[8];
    const float* m_cb   = (const float*)d_in[9];
    const float* m_xpW  = (const float*)d_in[10];
    const float* m_dtW  = (const float*)d_in[11];
    const float* m_dtb  = (const float*)d_in[12];
    const float* m_Alog = (const float*)d_in[13];
    const float* m_D    = (const float*)d_in[14];
    const float* m_outW = (const float*)d_in[15];
    const float* d_Wi   = (const float*)d_in[16];
    const float* d_bi   = (const float*)d_in[17];
    const float* d_bh   = (const float*)d_in[18];
    const float* d_Wo   = (const float*)d_in[19];
    const float* d_bo   = (const float*)d_in[20];
    float* out_f = (float*)d_out;
    float* ws = (float*)d_ws;

    // ---- workspace layout (floats), total 25,315,328 = 101.3 MB ----
    float* OUT   = ws;                 // 2,097,152
    float* XCR   = ws + 2097152;       // 4,194,304 (conv in; later HEND/PPROD/CPART2)
    float* Z     = ws + 6291456;       // 4,194,304
    float* XC    = ws + 10485760;      // 4,194,304 (post-conv f32; later OUTb)
    float* DBL   = ws + 14680064;      // 262,144
    float* DELTA = ws + 14942208;      // 4,194,304 (hosts xproj split-K partials)
    float* HINIT = ws + 19136512;      // 2,097,152
    float* BF    = ws + 21233664;      // 2,097,152 (bf16 activations)
    float* WT    = ws + 23330816;      // 1,853,440 (bf16 transposed weights)
    float* DBLF  = ws + 25184256;      // 131,072  (bf16 dbl copy)

    // aliases
    float* HEND   = XCR;
    float* PPROD  = XCR + 2097152;
    float* CPARTX = DELTA;
    float* CPART2 = XCR;
    __hip_bfloat16* Xb   = (__hip_bfloat16*)BF;              // 4096x128
    __hip_bfloat16* H1b  = (__hip_bfloat16*)(BF + 262144);   // 4096x512
    __hip_bfloat16* XNb  = (__hip_bfloat16*)BF;              // 4096x512
    __hip_bfloat16* XCb  = (__hip_bfloat16*)BF;              // 4096x1024
    __hip_bfloat16* YB   = (__hip_bfloat16*)BF;              // 4096x1024
    __hip_bfloat16* H2b  = (__hip_bfloat16*)BF;              // 4096x64
    __hip_bfloat16* OUTb = (__hip_bfloat16*)XC;              // 4096x512
    __hip_bfloat16* DBLb = (__hip_bfloat16*)DBLF;            // 4096x64

    // transposed bf16 weights (offsets in bf16 units)
    __hip_bfloat16* WTu     = (__hip_bfloat16*)WT;
    __hip_bfloat16* T_pWi   = WTu;            // [512][128]
    __hip_bfloat16* T_pWo   = WTu + 65536;    // [512][512]
    __hip_bfloat16* T_inW0  = WTu + 327680;   // [2048][512]
    __hip_bfloat16* T_inW1  = WTu + 1376256;
    __hip_bfloat16* T_xpW0  = WTu + 2424832;  // [64][1024]
    __hip_bfloat16* T_xpW1  = WTu + 2490368;
    __hip_bfloat16* T_outW0 = WTu + 2555904;  // [512][1024]
    __hip_bfloat16* T_outW1 = WTu + 3080192;
    __hip_bfloat16* T_dWi   = WTu + 3604480;  // [64][512]
    __hip_bfloat16* T_dtW0  = WTu + 3637248;  // [1024][32]
    __hip_bfloat16* T_dtW1  = WTu + 3670016;
    __hip_bfloat16* T_dWo   = WTu + 3702784;  // [64][64]

    const dim3 blk(256);

    // ---- all weight conversions + x cvt in one launch ----
    prep_k<<<dim3(PREP_BLOCKS), blk, 0, stream>>>(
        x, Xb, p_Wi, T_pWi, p_Wo, T_pWo, m_inW, T_inW0, T_inW1,
        m_xpW, T_xpW0, T_xpW1, m_outW, T_outW0, T_outW1,
        d_Wi, T_dWi, m_dtW, T_dtW0, T_dtW1, d_Wo, T_dWo);

    // ---- liquid1 ----
    mfma_gemm<128, 64, 64, 2, false><<<dim3(32, 8), blk, 0, stream>>>(
        (const ushort*)Xb, IN_, (const ushort*)T_pWi, IN_, nullptr, nullptr,
        p_bi, p_bh, nullptr, H1b, H_, M_TOK, H_, IN_);
    mfma_gemm<128, 64, 64, 3, false><<<dim3(32, 8), blk, 0, stream>>>(
        (const ushort*)H1b, H_, (const ushort*)T_pWo, H_, nullptr, nullptr,
        p_bo, nullptr, OUT, nullptr, H_, M_TOK, H_, H_);

    for (int l = 0; l < NL_; ++l) {
        const float* nw   = m_norm + l * H_;
        const float* cw   = m_cw   + l * ED_ * K_;
        const float* cb   = m_cb   + l * ED_;
        const float* dtb  = m_dtb  + l * ED_;
        const float* Alog = m_Alog + l * ED_ * N_;
        const float* Dv   = m_D    + l * ED_;
        const __hip_bfloat16* TinW  = l ? T_inW1  : T_inW0;
        const __hip_bfloat16* TxpW  = l ? T_xpW1  : T_xpW0;
        const __hip_bfloat16* ToutW = l ? T_outW1 : T_outW0;
        const __hip_bfloat16* TdtW  = l ? T_dtW1  : T_dtW0;

        rmsnorm_k<<<dim3(M_TOK), blk, 0, stream>>>(OUT, nw, XNb);
        // in_W: both halves in one dual launch (de-interleaved outputs)
        mfma_gemm<128, 128, 64, 0, true><<<dim3(32, 8, 2), blk, 0, stream>>>(
            (const ushort*)XNb, H_, (const ushort*)TinW, H_,
            (const ushort*)(TinW + (size_t)ED_ * H_), Z,
            nullptr, nullptr, XCR, nullptr, ED_, M_TOK, ED_, H_);
        conv_silu_k<<<dim3(M_TOK * ED_ / 4 / 256), blk, 0, stream>>>(XCR, cw, cb, XC, XCb);
        mfma_gemm<128, 64, 64, 4, false><<<dim3(32, 1, 8), blk, 0, stream>>>(
            (const ushort*)XCb, ED_, (const ushort*)TxpW, ED_, nullptr, nullptr,
            nullptr, nullptr, CPARTX, nullptr, 64, M_TOK, 64, ED_ / 8);
        reduce_part_k<8, 0, false, false, 2><<<dim3(1024), blk, 0, stream>>>(
            CPARTX, nullptr, nullptr, DBL, DBLb, M_TOK * 64, 64);
        mfma_gemm<128, 64, 32, 6, false><<<dim3(32, 16), blk, 0, stream>>>(
            (const ushort*)DBLb, 64, (const ushort*)TdtW, DR_, nullptr, nullptr,
            dtb, nullptr, DELTA, nullptr, ED_, M_TOK, ED_, DR_);
        ssm_scan_k<false><<<dim3(2048), blk, 0, stream>>>(
            DELTA, XC, DBL, nullptr, Alog, nullptr, HEND, PPROD, nullptr, nullptr);
        ssm_combine_k<<<dim3(128), blk, 0, stream>>>(HEND, PPROD, HINIT);
        ssm_scan_k<true><<<dim3(2048), blk, 0, stream>>>(
            DELTA, XC, DBL, Z, Alog, Dv, nullptr, nullptr, HINIT, YB);
        if (l == 0) {
            mfma_gemm<128, 64, 64, 1, false><<<dim3(32, 8), blk, 0, stream>>>(
                (const ushort*)YB, ED_, (const ushort*)ToutW, ED_, nullptr, nullptr,
                nullptr, nullptr, OUT, nullptr, H_, M_TOK, H_, ED_);
        } else {
            // fused: OUT += y@outW, and write bf16 copy for liquid2 input
            mfma_gemm<128, 64, 64, 7, false><<<dim3(32, 8), blk, 0, stream>>>(
                (const ushort*)YB, ED_, (const ushort*)ToutW, ED_, nullptr, nullptr,
                nullptr, nullptr, OUT, OUTb, H_, M_TOK, H_, ED_);
        }
    }

    // ---- liquid2 + final (fused v - tanh(v)) ----
    mfma_gemm<128, 64, 64, 4, false><<<dim3(32, 1, 8), blk, 0, stream>>>(
        (const ushort*)OUTb, H_, (const ushort*)T_dWi, H_, nullptr, nullptr,
        nullptr, nullptr, CPART2, nullptr, 64, M_TOK, 64, H_ / 8);
    reduce_part_k<8, 1, true, true, 1><<<dim3(1024), blk, 0, stream>>>(
        CPART2, d_bi, d_bh, nullptr, H2b, M_TOK * 64, 64);
    mfma_gemm<128, 64, 64, 5, false><<<dim3(32, 1), blk, 0, stream>>>(
        (const ushort*)H2b, OUT_, (const ushort*)T_dWo, OUT_, nullptr, nullptr,
        d_bo, nullptr, out_f, nullptr, OUT_, M_TOK, OUT_, OUT_);
}